// Round 1
// baseline (4369.746 us; speedup 1.0000x reference)
//
#include <hip/hip_runtime.h>
#include <math.h>

// Problem constants (from setup_inputs)
#define BATCH 256
#define NQ 30
#define NK 100
#define HID 512
#define WORD 300
#define NNODE 3
#define KIN 900          // WORD*NNODE
#define NANS 32000
#define NOUT 300
#define NLAYERS 3

// ---------------- reduction helpers (block of 256) ----------------
__device__ __forceinline__ float waveReduceSum(float v) {
#pragma unroll
  for (int o = 32; o > 0; o >>= 1) v += __shfl_xor(v, o);
  return v;
}
__device__ __forceinline__ float waveReduceMax(float v) {
#pragma unroll
  for (int o = 32; o > 0; o >>= 1) v = fmaxf(v, __shfl_xor(v, o));
  return v;
}
__device__ float blockReduceSum256(float v) {
  __shared__ float sm[4];
  int lane = threadIdx.x & 63, w = threadIdx.x >> 6;
  v = waveReduceSum(v);
  if (lane == 0) sm[w] = v;
  __syncthreads();
  float r = sm[0] + sm[1] + sm[2] + sm[3];
  __syncthreads();
  return r;
}
__device__ float blockReduceMax256(float v) {
  __shared__ float sm[4];
  int lane = threadIdx.x & 63, w = threadIdx.x >> 6;
  v = waveReduceMax(v);
  if (lane == 0) sm[w] = v;
  __syncthreads();
  float r = fmaxf(fmaxf(sm[0], sm[1]), fmaxf(sm[2], sm[3]));
  __syncthreads();
  return r;
}

// ---------------- generic tiled fp32 GEMM ----------------
// C[M,N] = op(A)[M,K] @ op(B)[K,N] (+bias) (+relu)
// GATHER: A[m,k] = emb[ids[m*3 + k/300]*300 + k%300] (NaN->0)
// TRANSB: B is stored [N,K] row-major (used for glove_cands)
#define BM 64
#define BN 64
#define BK 16

template <int GATHER, int TRANSB, int RELU, int BIAS>
__global__ __launch_bounds__(256) void gemm_k(
    const float* __restrict__ A, const int* __restrict__ ids,
    const float* __restrict__ emb, const float* __restrict__ B,
    const float* __restrict__ bias, float* __restrict__ C,
    int M, int N, int K) {
  __shared__ float As[BK][BM];
  __shared__ float Bs[BK][BN + 1];
  const int tid = threadIdx.x;
  const int tx = tid & 15, ty = tid >> 4;
  const int row0 = blockIdx.y * BM, col0 = blockIdx.x * BN;
  float acc[4][4] = {};

  for (int k0 = 0; k0 < K; k0 += BK) {
    // load A tile (1024 elems, 4 per thread)
#pragma unroll
    for (int e = tid; e < BM * BK; e += 256) {
      int kk = e >> 6, m = e & 63;  // e/BM, e%BM
      int gr = row0 + m, gk = k0 + kk;
      float v = 0.f;
      if (gr < M && gk < K) {
        if (GATHER) {
          int node = (gk >= 600) ? 2 : ((gk >= 300) ? 1 : 0);
          int off = gk - node * 300;
          int id = ids[gr * 3 + node];
          v = emb[(size_t)id * 300 + off];
          if (v != v) v = 0.f;  // NaN -> 0
        } else {
          v = A[(size_t)gr * K + gk];
        }
      }
      As[kk][m] = v;
    }
    // load B tile
    if (TRANSB) {
#pragma unroll
      for (int e = tid; e < BN * BK; e += 256) {
        int n = e >> 4, kk = e & 15;  // e/BK, e%BK : consecutive kk coalesced
        int gc = col0 + n, gk = k0 + kk;
        float v = 0.f;
        if (gc < N && gk < K) v = B[(size_t)gc * K + gk];
        Bs[kk][n] = v;
      }
    } else {
#pragma unroll
      for (int e = tid; e < BN * BK; e += 256) {
        int kk = e >> 6, n = e & 63;
        int gc = col0 + n, gk = k0 + kk;
        float v = 0.f;
        if (gc < N && gk < K) v = B[(size_t)gk * N + gc];
        Bs[kk][n] = v;
      }
    }
    __syncthreads();
#pragma unroll
    for (int kk = 0; kk < BK; ++kk) {
      float a[4], b[4];
#pragma unroll
      for (int i = 0; i < 4; ++i) a[i] = As[kk][ty * 4 + i];
#pragma unroll
      for (int j = 0; j < 4; ++j) b[j] = Bs[kk][tx * 4 + j];
#pragma unroll
      for (int i = 0; i < 4; ++i)
#pragma unroll
        for (int j = 0; j < 4; ++j) acc[i][j] += a[i] * b[j];
    }
    __syncthreads();
  }

#pragma unroll
  for (int i = 0; i < 4; ++i) {
    int r = row0 + ty * 4 + i;
    if (r >= M) continue;
#pragma unroll
    for (int j = 0; j < 4; ++j) {
      int cl = col0 + tx * 4 + j;
      if (cl >= N) continue;
      float v = acc[i][j];
      if (BIAS) v += bias[cl];
      if (RELU) v = fmaxf(v, 0.f);
      C[(size_t)r * N + cl] = v;
    }
  }
}

template <int GATHER, int TRANSB, int RELU, int BIAS>
static void launch_gemm(const float* A, const int* ids, const float* emb,
                        const float* Bm, const float* bias, float* C,
                        int M, int N, int K, hipStream_t stream) {
  dim3 grid((N + BN - 1) / BN, (M + BM - 1) / BM);
  gemm_k<GATHER, TRANSB, RELU, BIAS><<<grid, 256, 0, stream>>>(A, ids, emb, Bm, bias, C, M, N, K);
}

// ---------------- hyperbolic row ops ----------------
// out = proj(expmap0(proj_tan0(in), c), c), row-local over D dims, c = curv[ci]
__global__ __launch_bounds__(256) void expproj_kernel(
    const float* __restrict__ in, float* __restrict__ outp, int D,
    const float* __restrict__ curv, int ci) {
  const int row = blockIdx.x, tid = threadIdx.x;
  const float* x = in + (size_t)row * D;
  float* y = outp + (size_t)row * D;
  const float c = curv[ci];
  const float Kc = 1.f / c, sqrtK = sqrtf(Kc);
  float ss = 0.f;
  for (int d = 1 + tid; d < D; d += 256) {
    float v = x[d];
    ss += v * v;
  }
  ss = blockReduceSum256(ss);
  float n = fmaxf(sqrtf(ss), 1e-15f);
  float theta = n / sqrtK;
  float f = sqrtK * sinhf(theta) / n;     // scale applied to spatial dims
  float ss2 = f * f * ss;                 // ||spatial||^2 after expmap
  float first = sqrtf(fmaxf(Kc + ss2, 1e-7f));
  if (tid == 0) y[0] = first;
  for (int d = 1 + tid; d < D; d += 256) y[d] = f * x[d];
}

// out = proj_tan0(logmap0(in, c)); in-place safe
__global__ __launch_bounds__(256) void logmap_kernel(
    const float* __restrict__ in, float* __restrict__ outp, int D,
    const float* __restrict__ curv, int ci) {
  const int row = blockIdx.x, tid = threadIdx.x;
  const float* x = in + (size_t)row * D;
  float* y = outp + (size_t)row * D;
  const float c = curv[ci];
  const float Kc = 1.f / c, sqrtK = sqrtf(Kc);
  float x0 = x[0];
  float ss = 0.f;
  for (int d = 1 + tid; d < D; d += 256) {
    float v = x[d];
    ss += v * v;
  }
  ss = blockReduceSum256(ss);
  float n = fmaxf(sqrtf(ss), 1e-15f);
  float theta = fmaxf(x0 / sqrtK, 1.f + 1e-7f);
  float r = sqrtK * acoshf(theta) / n;
  if (tid == 0) y[0] = 0.f;
  for (int d = 1 + tid; d < D; d += 256) y[d] = r * x[d];
}

// ---------------- attention ----------------
// S[b,kr,q] = (1/sqrt(512)) * dot(kp[b,kr,:], qp[b,q,:])
__global__ __launch_bounds__(256) void s_kernel(
    const float* __restrict__ kp, const float* __restrict__ qp,
    float* __restrict__ S) {
  const int b = blockIdx.y, kr = blockIdx.x;
  __shared__ float kps[HID];
  __shared__ float red[8][33];
  const int tid = threadIdx.x;
  const float* kpr = kp + ((size_t)b * NK + kr) * HID;
  for (int d = tid; d < HID; d += 256) kps[d] = kpr[d];
  __syncthreads();
  const int q = tid & 31, g = tid >> 5;
  float part = 0.f;
  if (q < NQ) {
    const float4* qpr = (const float4*)(qp + ((size_t)b * NQ + q) * HID + g * 64);
#pragma unroll
    for (int i = 0; i < 16; ++i) {
      float4 v = qpr[i];
      part += kps[g * 64 + i * 4 + 0] * v.x + kps[g * 64 + i * 4 + 1] * v.y +
              kps[g * 64 + i * 4 + 2] * v.z + kps[g * 64 + i * 4 + 3] * v.w;
    }
  }
  red[g][q] = part;
  __syncthreads();
  if (tid < NQ) {
    float s = 0.f;
#pragma unroll
    for (int g2 = 0; g2 < 8; ++g2) s += red[g2][tid];
    S[((size_t)b * NK + kr) * NQ + tid] = s * 0.044194173824159216f;  // 1/sqrt(512)
  }
}

// att_k[b,kr,:] = softmax_q(S[b,kr,:]) @ qt[b] + kt[b,kr,:]
__global__ __launch_bounds__(256) void attk_kernel(
    const float* __restrict__ S, const float* __restrict__ qt,
    const float* __restrict__ kt, float* __restrict__ outp) {
  const int b = blockIdx.x, tid = threadIdx.x;
  __shared__ float qts[NQ * HID];  // 60 KB
  __shared__ float P[32];
  const float* qtb = qt + (size_t)b * NQ * HID;
  for (int e = tid; e < NQ * HID; e += 256) qts[e] = qtb[e];
  __syncthreads();
  for (int kr = 0; kr < NK; ++kr) {
    if (tid < 32) {
      float v = (tid < NQ) ? S[((size_t)b * NK + kr) * NQ + tid] : -1e30f;
      float m = v;
#pragma unroll
      for (int o = 16; o > 0; o >>= 1) m = fmaxf(m, __shfl_xor(m, o, 32));
      float e = (tid < NQ) ? expf(v - m) : 0.f;
      float ssum = e;
#pragma unroll
      for (int o = 16; o > 0; o >>= 1) ssum += __shfl_xor(ssum, o, 32);
      if (tid < NQ) P[tid] = e / ssum;
    }
    __syncthreads();
    const size_t base = ((size_t)b * NK + kr) * HID;
    float acc0 = kt[base + tid];
    float acc1 = kt[base + tid + 256];
#pragma unroll
    for (int q = 0; q < NQ; ++q) {
      float p = P[q];
      acc0 += p * qts[q * HID + tid];
      acc1 += p * qts[q * HID + tid + 256];
    }
    outp[base + tid] = acc0;
    outp[base + tid + 256] = acc1;
    __syncthreads();
  }
}

// att_q[b,qr,:] = softmax_k(S[b,:,qr]) @ kt[b] + qt[b,qr,:]
__global__ __launch_bounds__(256) void attq_kernel(
    const float* __restrict__ S, const float* __restrict__ kt,
    const float* __restrict__ qt, float* __restrict__ outp) {
  const int b = blockIdx.y, qr = blockIdx.x;
  const int tid = threadIdx.x;
  __shared__ float P[128];
  float v = (tid < NK) ? S[((size_t)b * NK + tid) * NQ + qr] : -1e30f;
  float m = blockReduceMax256(v);
  float e = (tid < NK) ? expf(v - m) : 0.f;
  float s = blockReduceSum256(e);
  if (tid < NK) P[tid] = e / s;
  __syncthreads();
  const size_t qbase = ((size_t)b * NQ + qr) * HID;
  float acc0 = qt[qbase + tid];
  float acc1 = qt[qbase + tid + 256];
  for (int kr = 0; kr < NK; ++kr) {
    float p = P[kr];
    const size_t kbase = ((size_t)b * NK + kr) * HID;
    acc0 += p * kt[kbase + tid];
    acc1 += p * kt[kbase + tid + 256];
  }
  outp[qbase + tid] = acc0;
  outp[qbase + tid + 256] = acc1;
}

// ---------------- tail ----------------
__global__ __launch_bounds__(512) void mean_kernel(
    const float* __restrict__ kx, const float* __restrict__ qx,
    float* __restrict__ last) {
  const int b = blockIdx.x, tid = threadIdx.x;
  float sk = 0.f;
  for (int r = 0; r < NK; ++r) sk += kx[((size_t)b * NK + r) * HID + tid];
  float sq = 0.f;
  for (int r = 0; r < NQ; ++r) sq += qx[((size_t)b * NQ + r) * HID + tid];
  last[(size_t)b * 1024 + tid] = sk * (1.f / NK);
  last[(size_t)b * 1024 + HID + tid] = sq * (1.f / NQ);
}

__global__ __launch_bounds__(256) void logsoftmax_kernel(float* __restrict__ x, int N) {
  const int b = blockIdx.x, tid = threadIdx.x;
  float* row = x + (size_t)b * N;
  float m = -3.4e38f;
  for (int i = tid; i < N; i += 256) m = fmaxf(m, row[i]);
  m = blockReduceMax256(m);
  float s = 0.f;
  for (int i = tid; i < N; i += 256) s += expf(row[i] - m);
  s = blockReduceSum256(s);
  float lse = m + logf(s);
  for (int i = tid; i < N; i += 256) row[i] -= lse;
}

// ---------------- launch ----------------
extern "C" void kernel_launch(void* const* d_in, const int* in_sizes, int n_in,
                              void* d_out, int out_size, void* d_ws, size_t ws_size,
                              hipStream_t stream) {
  const int* qid = (const int*)d_in[0];
  const int* kid = (const int*)d_in[1];
  const float* emb = (const float*)d_in[2];
  const float* q2h_w = (const float*)d_in[3];
  const float* q2h_b = (const float*)d_in[4];
  const float* k2h_w = (const float*)d_in[5];
  const float* k2h_b = (const float*)d_in[6];
  const float* Wk = (const float*)d_in[7];
  const float* Wq = (const float*)d_in[8];
  const float* curv = (const float*)d_in[9];
  const float* p1w = (const float*)d_in[10];
  const float* p1b = (const float*)d_in[11];
  const float* p2w = (const float*)d_in[12];
  const float* p2b = (const float*)d_in[13];
  const float* glove = (const float*)d_in[14];
  float* out = (float*)d_out;
  float* ws = (float*)d_ws;

  const int MK = BATCH * NK;  // 25600
  const int MQ = BATCH * NQ;  // 7680

  float* Xk = ws;                         // 25600*512  (k / kt)
  float* Ak = Xk + (size_t)MK * HID;      // 25600*512  (kp / att_k)
  float* Xq = Ak + (size_t)MK * HID;      // 7680*512   (q / qt)
  float* Aq = Xq + (size_t)MQ * HID;      // 7680*512   (qp / att_q)
  float* S = Aq + (size_t)MQ * HID;       // 256*100*30
  float* last = S + (size_t)BATCH * NK * NQ;  // 256*1024
  float* h1 = last + (size_t)BATCH * 1024;    // 256*512
  float* o2 = h1 + (size_t)BATCH * HID;       // 256*300

  // input projections (fused gather) -> Xq, Xk
  launch_gemm<1, 0, 0, 1>(nullptr, qid, emb, q2h_w, q2h_b, Xq, MQ, HID, KIN, stream);
  launch_gemm<1, 0, 0, 1>(nullptr, kid, emb, k2h_w, k2h_b, Xk, MK, HID, KIN, stream);

  // initial hyperbolic embedding (in-place)
  expproj_kernel<<<MQ, 256, 0, stream>>>(Xq, Xq, HID, curv, 0);
  expproj_kernel<<<MK, 256, 0, stream>>>(Xk, Xk, HID, curv, 0);

  for (int i = 0; i < NLAYERS; ++i) {
    // tangent-space (in-place): Xk = kt, Xq = qt
    logmap_kernel<<<MK, 256, 0, stream>>>(Xk, Xk, HID, curv, i);
    logmap_kernel<<<MQ, 256, 0, stream>>>(Xq, Xq, HID, curv, i);
    // projections kp/qp
    launch_gemm<0, 0, 0, 0>(Xk, nullptr, nullptr, Wk + (size_t)i * HID * HID, nullptr, Ak, MK, HID, HID, stream);
    launch_gemm<0, 0, 0, 0>(Xq, nullptr, nullptr, Wq + (size_t)i * HID * HID, nullptr, Aq, MQ, HID, HID, stream);
    // scores
    s_kernel<<<dim3(NK, BATCH), 256, 0, stream>>>(Ak, Aq, S);
    // attention (write att into Ak/Aq; kp/qp are dead)
    attk_kernel<<<BATCH, 256, 0, stream>>>(S, Xq, Xk, Ak);
    attq_kernel<<<dim3(NQ, BATCH), 256, 0, stream>>>(S, Xk, Xq, Aq);
    // back to hyperbolic
    expproj_kernel<<<MK, 256, 0, stream>>>(Ak, Xk, HID, curv, i + 1);
    expproj_kernel<<<MQ, 256, 0, stream>>>(Aq, Xq, HID, curv, i + 1);
  }

  // mean over nodes, concat -> last (B,1024)
  mean_kernel<<<BATCH, 512, 0, stream>>>(Xk, Xq, last);
  // logmap on the 1024-dim concat (in-place)
  logmap_kernel<<<BATCH, 256, 0, stream>>>(last, last, 1024, curv, NLAYERS);
  // proj1 + relu
  launch_gemm<0, 0, 1, 1>(last, nullptr, nullptr, p1w, p1b, h1, BATCH, HID, 1024, stream);
  // proj2
  launch_gemm<0, 0, 0, 1>(h1, nullptr, nullptr, p2w, p2b, o2, BATCH, NOUT, HID, stream);
  // sim = o2 @ glove^T -> d_out
  launch_gemm<0, 1, 0, 0>(o2, nullptr, nullptr, glove, nullptr, out, BATCH, NANS, NOUT, stream);
  // log_softmax in place
  logsoftmax_kernel<<<BATCH, 256, 0, stream>>>(out, NANS);
}

// Round 2
// 3247.799 us; speedup vs baseline: 1.3454x; 1.3454x over previous
//
#include <hip/hip_runtime.h>
#include <math.h>

// Problem constants (from setup_inputs)
#define BATCH 256
#define NQ 30
#define NK 100
#define HID 512
#define WORD 300
#define NNODE 3
#define KIN 900          // WORD*NNODE
#define NANS 32000
#define NOUT 300
#define NLAYERS 3

// ---------------- reduction helpers (block of 256) ----------------
__device__ __forceinline__ float waveReduceSum(float v) {
#pragma unroll
  for (int o = 32; o > 0; o >>= 1) v += __shfl_xor(v, o);
  return v;
}
__device__ __forceinline__ float waveReduceMax(float v) {
#pragma unroll
  for (int o = 32; o > 0; o >>= 1) v = fmaxf(v, __shfl_xor(v, o));
  return v;
}
__device__ float blockReduceSum256(float v) {
  __shared__ float sm[4];
  int lane = threadIdx.x & 63, w = threadIdx.x >> 6;
  v = waveReduceSum(v);
  if (lane == 0) sm[w] = v;
  __syncthreads();
  float r = sm[0] + sm[1] + sm[2] + sm[3];
  __syncthreads();
  return r;
}
__device__ float blockReduceMax256(float v) {
  __shared__ float sm[4];
  int lane = threadIdx.x & 63, w = threadIdx.x >> 6;
  v = waveReduceMax(v);
  if (lane == 0) sm[w] = v;
  __syncthreads();
  float r = fmaxf(fmaxf(sm[0], sm[1]), fmaxf(sm[2], sm[3]));
  __syncthreads();
  return r;
}

// ---------------- tiled fp32 GEMM (v2: vectorized LDS, 2x2 chunked frags) --
// C[M,N] = op(A)[M,K] @ op(B)[K,N] (+bias) (+relu)
// GATHER: A[m,k] = emb[ids[m*3 + k/300]*300 + k%300] (NaN->0)
// TRANSB: B is stored [N,K] row-major (glove_cands)
// CH: tile = (64*CH) x (64*CH); per-thread = (4*CH) x (4*CH) as CH x CH
//     chunks of 4x4, chunk stride 64 (so all LDS frag reads are b128 with
//     stride-4-float lane addressing -> 2-way bank aliasing = free).
// BK = 16. LDS rows padded +4 floats: keeps 16B alignment, breaks transpose
// write conflicts.

template <int CH, int GATHER, int TRANSB, int RELU, int BIAS>
__global__ __launch_bounds__(256) void gemm_k(
    const float* __restrict__ A, const int* __restrict__ ids,
    const float* __restrict__ emb, const float* __restrict__ B,
    const float* __restrict__ bias, float* __restrict__ C,
    int M, int N, int K) {
  constexpr int BMv = 64 * CH, BNv = 64 * CH, BKv = 16;
  constexpr int LDA = BMv + 4, LDB = BNv + 4;
  __shared__ float As[BKv][LDA];
  __shared__ float Bs[BKv][LDB];
  const int tid = threadIdx.x;
  const int tx = tid & 15, ty = tid >> 4;
  const int row0 = blockIdx.y * BMv, col0 = blockIdx.x * BNv;
  float acc[CH][CH][4][4] = {};

  for (int k0 = 0; k0 < K; k0 += BKv) {
    // ---- A tile: As[kk][m] = Aval(row0+m, k0+kk), loaded as float4 along K
#pragma unroll
    for (int l = 0; l < CH; ++l) {
      int e = tid + l * 256;     // float4 slot; 4 slots per row
      int m = e >> 2;
      int kk = (e & 3) * 4;
      int gr = row0 + m, gk = k0 + kk;
      float4 v = make_float4(0.f, 0.f, 0.f, 0.f);
      if (gr < M && gk < K) {  // K%4==0 for all our K -> float4 fully valid
        if (GATHER) {
          int node = (gk >= 600) ? 2 : ((gk >= 300) ? 1 : 0);
          int off = gk - node * 300;   // 300%4==0: float4 never straddles
          int id = ids[gr * 3 + node];
          v = *(const float4*)(emb + (size_t)id * 300 + off);
          if (v.x != v.x) v.x = 0.f;
          if (v.y != v.y) v.y = 0.f;
          if (v.z != v.z) v.z = 0.f;
          if (v.w != v.w) v.w = 0.f;
        } else {
          v = *(const float4*)(A + (size_t)gr * K + gk);
        }
      }
      As[kk + 0][m] = v.x;
      As[kk + 1][m] = v.y;
      As[kk + 2][m] = v.z;
      As[kk + 3][m] = v.w;
    }
    // ---- B tile ----
    if (TRANSB) {
#pragma unroll
      for (int l = 0; l < CH; ++l) {
        int e = tid + l * 256;
        int n = e >> 2;
        int kk = (e & 3) * 4;
        int gc = col0 + n, gk = k0 + kk;
        float4 v = make_float4(0.f, 0.f, 0.f, 0.f);
        if (gc < N && gk < K) v = *(const float4*)(B + (size_t)gc * K + gk);
        Bs[kk + 0][n] = v.x;
        Bs[kk + 1][n] = v.y;
        Bs[kk + 2][n] = v.z;
        Bs[kk + 3][n] = v.w;
      }
    } else {
#pragma unroll
      for (int l = 0; l < CH; ++l) {
        int e = tid + l * 256;
        int kk = e / (BNv / 4);
        int n = (e % (BNv / 4)) * 4;
        int gk = k0 + kk, gc = col0 + n;
        float4 v = make_float4(0.f, 0.f, 0.f, 0.f);
        if (gk < K && gc < N) v = *(const float4*)(B + (size_t)gk * N + gc);
        *(float4*)&Bs[kk][n] = v;
      }
    }
    __syncthreads();
#pragma unroll
    for (int kk = 0; kk < BKv; ++kk) {
      float a[CH][4], b[CH][4];
#pragma unroll
      for (int c = 0; c < CH; ++c) {
        float4 t = *(const float4*)&As[kk][c * 64 + ty * 4];
        a[c][0] = t.x; a[c][1] = t.y; a[c][2] = t.z; a[c][3] = t.w;
      }
#pragma unroll
      for (int c = 0; c < CH; ++c) {
        float4 t = *(const float4*)&Bs[kk][c * 64 + tx * 4];
        b[c][0] = t.x; b[c][1] = t.y; b[c][2] = t.z; b[c][3] = t.w;
      }
#pragma unroll
      for (int ci = 0; ci < CH; ++ci)
#pragma unroll
        for (int cj = 0; cj < CH; ++cj)
#pragma unroll
          for (int i = 0; i < 4; ++i)
#pragma unroll
            for (int j = 0; j < 4; ++j)
              acc[ci][cj][i][j] += a[ci][i] * b[cj][j];
    }
    __syncthreads();
  }

  // ---- epilogue: float4 stores ----
#pragma unroll
  for (int ci = 0; ci < CH; ++ci)
#pragma unroll
    for (int i = 0; i < 4; ++i) {
      int r = row0 + ci * 64 + ty * 4 + i;
      if (r >= M) continue;
#pragma unroll
      for (int cj = 0; cj < CH; ++cj) {
        int cl = col0 + cj * 64 + tx * 4;
        if (cl >= N) continue;  // N%4==0 -> float4 fully valid
        float4 v = make_float4(acc[ci][cj][i][0], acc[ci][cj][i][1],
                               acc[ci][cj][i][2], acc[ci][cj][i][3]);
        if (BIAS) {
          float4 bb = *(const float4*)(bias + cl);
          v.x += bb.x; v.y += bb.y; v.z += bb.z; v.w += bb.w;
        }
        if (RELU) {
          v.x = fmaxf(v.x, 0.f); v.y = fmaxf(v.y, 0.f);
          v.z = fmaxf(v.z, 0.f); v.w = fmaxf(v.w, 0.f);
        }
        *(float4*)(C + (size_t)r * N + cl) = v;
      }
    }
}

template <int CH, int GATHER, int TRANSB, int RELU, int BIAS>
static void launch_gemm(const float* A, const int* ids, const float* emb,
                        const float* Bm, const float* bias, float* C,
                        int M, int N, int K, hipStream_t stream) {
  constexpr int BMv = 64 * CH, BNv = 64 * CH;
  dim3 grid((N + BNv - 1) / BNv, (M + BMv - 1) / BMv);
  gemm_k<CH, GATHER, TRANSB, RELU, BIAS><<<grid, 256, 0, stream>>>(A, ids, emb, Bm, bias, C, M, N, K);
}

// ---------------- hyperbolic row ops ----------------
__global__ __launch_bounds__(256) void expproj_kernel(
    const float* __restrict__ in, float* __restrict__ outp, int D,
    const float* __restrict__ curv, int ci) {
  const int row = blockIdx.x, tid = threadIdx.x;
  const float* x = in + (size_t)row * D;
  float* y = outp + (size_t)row * D;
  const float c = curv[ci];
  const float Kc = 1.f / c, sqrtK = sqrtf(Kc);
  float ss = 0.f;
  for (int d = 1 + tid; d < D; d += 256) {
    float v = x[d];
    ss += v * v;
  }
  ss = blockReduceSum256(ss);
  float n = fmaxf(sqrtf(ss), 1e-15f);
  float theta = n / sqrtK;
  float f = sqrtK * sinhf(theta) / n;
  float ss2 = f * f * ss;
  float first = sqrtf(fmaxf(Kc + ss2, 1e-7f));
  if (tid == 0) y[0] = first;
  for (int d = 1 + tid; d < D; d += 256) y[d] = f * x[d];
}

__global__ __launch_bounds__(256) void logmap_kernel(
    const float* __restrict__ in, float* __restrict__ outp, int D,
    const float* __restrict__ curv, int ci) {
  const int row = blockIdx.x, tid = threadIdx.x;
  const float* x = in + (size_t)row * D;
  float* y = outp + (size_t)row * D;
  const float c = curv[ci];
  const float Kc = 1.f / c, sqrtK = sqrtf(Kc);
  float x0 = x[0];
  float ss = 0.f;
  for (int d = 1 + tid; d < D; d += 256) {
    float v = x[d];
    ss += v * v;
  }
  ss = blockReduceSum256(ss);
  float n = fmaxf(sqrtf(ss), 1e-15f);
  float theta = fmaxf(x0 / sqrtK, 1.f + 1e-7f);
  float r = sqrtK * acoshf(theta) / n;
  if (tid == 0) y[0] = 0.f;
  for (int d = 1 + tid; d < D; d += 256) y[d] = r * x[d];
}

// ---------------- attention ----------------
__global__ __launch_bounds__(256) void s_kernel(
    const float* __restrict__ kp, const float* __restrict__ qp,
    float* __restrict__ S) {
  const int b = blockIdx.y, kr = blockIdx.x;
  __shared__ float kps[HID];
  __shared__ float red[8][33];
  const int tid = threadIdx.x;
  const float* kpr = kp + ((size_t)b * NK + kr) * HID;
  for (int d = tid; d < HID; d += 256) kps[d] = kpr[d];
  __syncthreads();
  const int q = tid & 31, g = tid >> 5;
  float part = 0.f;
  if (q < NQ) {
    const float4* qpr = (const float4*)(qp + ((size_t)b * NQ + q) * HID + g * 64);
#pragma unroll
    for (int i = 0; i < 16; ++i) {
      float4 v = qpr[i];
      part += kps[g * 64 + i * 4 + 0] * v.x + kps[g * 64 + i * 4 + 1] * v.y +
              kps[g * 64 + i * 4 + 2] * v.z + kps[g * 64 + i * 4 + 3] * v.w;
    }
  }
  red[g][q] = part;
  __syncthreads();
  if (tid < NQ) {
    float s = 0.f;
#pragma unroll
    for (int g2 = 0; g2 < 8; ++g2) s += red[g2][tid];
    S[((size_t)b * NK + kr) * NQ + tid] = s * 0.044194173824159216f;
  }
}

__global__ __launch_bounds__(256) void attk_kernel(
    const float* __restrict__ S, const float* __restrict__ qt,
    const float* __restrict__ kt, float* __restrict__ outp) {
  const int b = blockIdx.x, tid = threadIdx.x;
  __shared__ float qts[NQ * HID];  // 60 KB
  __shared__ float P[32];
  const float* qtb = qt + (size_t)b * NQ * HID;
  for (int e = tid; e < NQ * HID; e += 256) qts[e] = qtb[e];
  __syncthreads();
  for (int kr = 0; kr < NK; ++kr) {
    if (tid < 32) {
      float v = (tid < NQ) ? S[((size_t)b * NK + kr) * NQ + tid] : -1e30f;
      float m = v;
#pragma unroll
      for (int o = 16; o > 0; o >>= 1) m = fmaxf(m, __shfl_xor(m, o, 32));
      float e = (tid < NQ) ? expf(v - m) : 0.f;
      float ssum = e;
#pragma unroll
      for (int o = 16; o > 0; o >>= 1) ssum += __shfl_xor(ssum, o, 32);
      if (tid < NQ) P[tid] = e / ssum;
    }
    __syncthreads();
    const size_t base = ((size_t)b * NK + kr) * HID;
    float acc0 = kt[base + tid];
    float acc1 = kt[base + tid + 256];
#pragma unroll
    for (int q = 0; q < NQ; ++q) {
      float p = P[q];
      acc0 += p * qts[q * HID + tid];
      acc1 += p * qts[q * HID + tid + 256];
    }
    outp[base + tid] = acc0;
    outp[base + tid + 256] = acc1;
    __syncthreads();
  }
}

__global__ __launch_bounds__(256) void attq_kernel(
    const float* __restrict__ S, const float* __restrict__ kt,
    const float* __restrict__ qt, float* __restrict__ outp) {
  const int b = blockIdx.y, qr = blockIdx.x;
  const int tid = threadIdx.x;
  __shared__ float P[128];
  float v = (tid < NK) ? S[((size_t)b * NK + tid) * NQ + qr] : -1e30f;
  float m = blockReduceMax256(v);
  float e = (tid < NK) ? expf(v - m) : 0.f;
  float s = blockReduceSum256(e);
  if (tid < NK) P[tid] = e / s;
  __syncthreads();
  const size_t qbase = ((size_t)b * NQ + qr) * HID;
  float acc0 = qt[qbase + tid];
  float acc1 = qt[qbase + tid + 256];
  for (int kr = 0; kr < NK; ++kr) {
    float p = P[kr];
    const size_t kbase = ((size_t)b * NK + kr) * HID;
    acc0 += p * kt[kbase + tid];
    acc1 += p * kt[kbase + tid + 256];
  }
  outp[qbase + tid] = acc0;
  outp[qbase + tid + 256] = acc1;
}

// ---------------- tail ----------------
__global__ __launch_bounds__(512) void mean_kernel(
    const float* __restrict__ kx, const float* __restrict__ qx,
    float* __restrict__ last) {
  const int b = blockIdx.x, tid = threadIdx.x;
  float sk = 0.f;
  for (int r = 0; r < NK; ++r) sk += kx[((size_t)b * NK + r) * HID + tid];
  float sq = 0.f;
  for (int r = 0; r < NQ; ++r) sq += qx[((size_t)b * NQ + r) * HID + tid];
  last[(size_t)b * 1024 + tid] = sk * (1.f / NK);
  last[(size_t)b * 1024 + HID + tid] = sq * (1.f / NQ);
}

__global__ __launch_bounds__(256) void logsoftmax_kernel(float* __restrict__ x, int N) {
  const int b = blockIdx.x, tid = threadIdx.x;
  float* row = x + (size_t)b * N;
  float m = -3.4e38f;
  for (int i = tid; i < N; i += 256) m = fmaxf(m, row[i]);
  m = blockReduceMax256(m);
  float s = 0.f;
  for (int i = tid; i < N; i += 256) s += expf(row[i] - m);
  s = blockReduceSum256(s);
  float lse = m + logf(s);
  for (int i = tid; i < N; i += 256) row[i] -= lse;
}

// ---------------- launch ----------------
extern "C" void kernel_launch(void* const* d_in, const int* in_sizes, int n_in,
                              void* d_out, int out_size, void* d_ws, size_t ws_size,
                              hipStream_t stream) {
  const int* qid = (const int*)d_in[0];
  const int* kid = (const int*)d_in[1];
  const float* emb = (const float*)d_in[2];
  const float* q2h_w = (const float*)d_in[3];
  const float* q2h_b = (const float*)d_in[4];
  const float* k2h_w = (const float*)d_in[5];
  const float* k2h_b = (const float*)d_in[6];
  const float* Wk = (const float*)d_in[7];
  const float* Wq = (const float*)d_in[8];
  const float* curv = (const float*)d_in[9];
  const float* p1w = (const float*)d_in[10];
  const float* p1b = (const float*)d_in[11];
  const float* p2w = (const float*)d_in[12];
  const float* p2b = (const float*)d_in[13];
  const float* glove = (const float*)d_in[14];
  float* out = (float*)d_out;
  float* ws = (float*)d_ws;

  const int MK = BATCH * NK;  // 25600
  const int MQ = BATCH * NQ;  // 7680

  float* Xk = ws;                         // 25600*512  (k / kt)
  float* Ak = Xk + (size_t)MK * HID;      // 25600*512  (kp / att_k)
  float* Xq = Ak + (size_t)MK * HID;      // 7680*512   (q / qt)
  float* Aq = Xq + (size_t)MQ * HID;      // 7680*512   (qp / att_q)
  float* S = Aq + (size_t)MQ * HID;       // 256*100*30
  float* last = S + (size_t)BATCH * NK * NQ;  // 256*1024
  float* h1 = last + (size_t)BATCH * 1024;    // 256*512
  float* o2 = h1 + (size_t)BATCH * HID;       // 256*300

  // input projections (fused gather) -> Xq, Xk
  launch_gemm<2, 1, 0, 0, 1>(nullptr, qid, emb, q2h_w, q2h_b, Xq, MQ, HID, KIN, stream);
  launch_gemm<2, 1, 0, 0, 1>(nullptr, kid, emb, k2h_w, k2h_b, Xk, MK, HID, KIN, stream);

  // initial hyperbolic embedding (in-place)
  expproj_kernel<<<MQ, 256, 0, stream>>>(Xq, Xq, HID, curv, 0);
  expproj_kernel<<<MK, 256, 0, stream>>>(Xk, Xk, HID, curv, 0);

  for (int i = 0; i < NLAYERS; ++i) {
    logmap_kernel<<<MK, 256, 0, stream>>>(Xk, Xk, HID, curv, i);
    logmap_kernel<<<MQ, 256, 0, stream>>>(Xq, Xq, HID, curv, i);
    launch_gemm<2, 0, 0, 0, 0>(Xk, nullptr, nullptr, Wk + (size_t)i * HID * HID, nullptr, Ak, MK, HID, HID, stream);
    launch_gemm<2, 0, 0, 0, 0>(Xq, nullptr, nullptr, Wq + (size_t)i * HID * HID, nullptr, Aq, MQ, HID, HID, stream);
    s_kernel<<<dim3(NK, BATCH), 256, 0, stream>>>(Ak, Aq, S);
    attk_kernel<<<BATCH, 256, 0, stream>>>(S, Xq, Xk, Ak);
    attq_kernel<<<dim3(NQ, BATCH), 256, 0, stream>>>(S, Xk, Xq, Aq);
    expproj_kernel<<<MK, 256, 0, stream>>>(Ak, Xk, HID, curv, i + 1);
    expproj_kernel<<<MQ, 256, 0, stream>>>(Aq, Xq, HID, curv, i + 1);
  }

  mean_kernel<<<BATCH, 512, 0, stream>>>(Xk, Xq, last);
  logmap_kernel<<<BATCH, 256, 0, stream>>>(last, last, 1024, curv, NLAYERS);
  launch_gemm<1, 0, 0, 1, 1>(last, nullptr, nullptr, p1w, p1b, h1, BATCH, HID, 1024, stream);
  launch_gemm<1, 0, 0, 0, 1>(h1, nullptr, nullptr, p2w, p2b, o2, BATCH, NOUT, HID, stream);
  launch_gemm<2, 0, 1, 0, 0>(o2, nullptr, nullptr, glove, nullptr, out, BATCH, NANS, NOUT, stream);
  logsoftmax_kernel<<<BATCH, 256, 0, stream>>>(out, NANS);
}

// Round 3
// 1976.232 us; speedup vs baseline: 2.2112x; 1.6434x over previous
//
#include <hip/hip_runtime.h>
#include <math.h>

// Problem constants (from setup_inputs)
#define BATCH 256
#define NQ 30
#define NK 100
#define HID 512
#define WORD 300
#define KIN 900          // WORD*3
#define KP 928           // KIN padded to multiple of 32
#define NANS 32000
#define NOUT 300
#define NLAYERS 3

typedef __attribute__((ext_vector_type(8))) short bf16x8;
typedef __attribute__((ext_vector_type(4))) float f32x4;
typedef unsigned short ushort_t;

__device__ __forceinline__ unsigned short f2bf(float f) {
  unsigned int u = __float_as_uint(f);
  u = (u + 0x7FFF + ((u >> 16) & 1)) >> 16;  // RNE
  return (unsigned short)u;
}

typedef const __attribute__((address_space(1))) unsigned int* gas_u32;
typedef __attribute__((address_space(3))) unsigned int* las_u32;
__device__ __forceinline__ void gld_lds16(const void* g, void* l) {
  __builtin_amdgcn_global_load_lds((gas_u32)g, (las_u32)l, 16, 0, 0);
}

// ---------------- reduction helpers ----------------
__device__ __forceinline__ float waveReduceSum(float v) {
#pragma unroll
  for (int o = 32; o > 0; o >>= 1) v += __shfl_xor(v, o);
  return v;
}
__device__ __forceinline__ float waveReduceMax(float v) {
#pragma unroll
  for (int o = 32; o > 0; o >>= 1) v = fmaxf(v, __shfl_xor(v, o));
  return v;
}
__device__ float blockReduceSum256(float v) {
  __shared__ float sm[4];
  int lane = threadIdx.x & 63, w = threadIdx.x >> 6;
  v = waveReduceSum(v);
  if (lane == 0) sm[w] = v;
  __syncthreads();
  float r = sm[0] + sm[1] + sm[2] + sm[3];
  __syncthreads();
  return r;
}
__device__ float blockReduceMax256(float v) {
  __shared__ float sm[4];
  int lane = threadIdx.x & 63, w = threadIdx.x >> 6;
  v = waveReduceMax(v);
  if (lane == 0) sm[w] = v;
  __syncthreads();
  float r = fmaxf(fmaxf(sm[0], sm[1]), fmaxf(sm[2], sm[3]));
  __syncthreads();
  return r;
}

// ---------------- bf16 MFMA GEMM ----------------
// C[M,N] (f32) = A[M,K] (bf16) @ Bt[N,K]^T (bf16)  (+bias)
// Requires: M%128==0, N%128==0, K%32==0. 4 waves, 128x128 tile, BK=32.
// LDS layout: 8 chunks per tile; chunk cb = 16 rows x 32 k = 1KB contiguous:
//   byte addr = cb*1024 + (kq*16 + rl)*16  (kq = k/8 quarter, rl = row%16)
// Staged with global_load_lds (dest linear in lane): lane l -> rl=l&15, kq=l>>4.
// Fragment read: lane l reads 16B at chunk_base + l*16 -> A[m=l&15][k=(l>>4)*8+j]
// (exactly the mfma_f32_16x16x32_bf16 A/B fragment layout).
template <int BIAS>
__global__ __launch_bounds__(256) void mfma_gemm(
    const ushort_t* __restrict__ A, const ushort_t* __restrict__ Bt,
    const float* __restrict__ bias, float* __restrict__ C,
    int M, int N, int K) {
  __shared__ __align__(16) ushort_t Abuf[128 * 32];
  __shared__ __align__(16) ushort_t Bbuf[128 * 32];
  const int tid = threadIdx.x;
  const int lane = tid & 63, w = tid >> 6;
  const int wr = w >> 1, wc = w & 1;
  const int row0 = blockIdx.y * 128, col0 = blockIdx.x * 128;
  const int s_r = lane & 15, s_kq = lane >> 4;

  // per-lane staging source offsets (elements)
  const size_t a_src0 = (size_t)(row0 + (w * 2 + 0) * 16 + s_r) * K + s_kq * 8;
  const size_t a_src1 = (size_t)(row0 + (w * 2 + 1) * 16 + s_r) * K + s_kq * 8;
  const size_t b_src0 = (size_t)(col0 + (w * 2 + 0) * 16 + s_r) * K + s_kq * 8;
  const size_t b_src1 = (size_t)(col0 + (w * 2 + 1) * 16 + s_r) * K + s_kq * 8;
  ushort_t* a_dst0 = Abuf + (w * 2 + 0) * 512;
  ushort_t* a_dst1 = Abuf + (w * 2 + 1) * 512;
  ushort_t* b_dst0 = Bbuf + (w * 2 + 0) * 512;
  ushort_t* b_dst1 = Bbuf + (w * 2 + 1) * 512;

  f32x4 acc[4][4];
#pragma unroll
  for (int i = 0; i < 4; ++i)
#pragma unroll
    for (int j = 0; j < 4; ++j) acc[i][j] = (f32x4){0.f, 0.f, 0.f, 0.f};

  for (int k0 = 0; k0 < K; k0 += 32) {
    gld_lds16(A + a_src0 + k0, a_dst0);
    gld_lds16(A + a_src1 + k0, a_dst1);
    gld_lds16(Bt + b_src0 + k0, b_dst0);
    gld_lds16(Bt + b_src1 + k0, b_dst1);
    __syncthreads();  // drains vmcnt -> LDS ready
    bf16x8 af[4], bfr[4];
#pragma unroll
    for (int mi = 0; mi < 4; ++mi)
      af[mi] = *(const bf16x8*)(Abuf + (wr * 4 + mi) * 512 + lane * 8);
#pragma unroll
    for (int nj = 0; nj < 4; ++nj)
      bfr[nj] = *(const bf16x8*)(Bbuf + (wc * 4 + nj) * 512 + lane * 8);
#pragma unroll
    for (int mi = 0; mi < 4; ++mi)
#pragma unroll
      for (int nj = 0; nj < 4; ++nj)
        acc[mi][nj] = __builtin_amdgcn_mfma_f32_16x16x32_bf16(
            af[mi], bfr[nj], acc[mi][nj], 0, 0, 0);
    __syncthreads();  // all reads done before next stage
  }

#pragma unroll
  for (int nj = 0; nj < 4; ++nj) {
    const int n = col0 + wc * 64 + nj * 16 + (lane & 15);
    const float bb = BIAS ? bias[n] : 0.f;
#pragma unroll
    for (int mi = 0; mi < 4; ++mi) {
      f32x4 v = acc[mi][nj];
#pragma unroll
      for (int r = 0; r < 4; ++r) {
        const int m = row0 + wr * 64 + mi * 16 + (lane >> 4) * 4 + r;
        C[(size_t)m * N + n] = v[r] + bb;
      }
    }
  }
}

template <int BIAS>
static void launch_mfma(const ushort_t* A, const ushort_t* Bt, const float* bias,
                        float* C, int M, int N, int K, hipStream_t s) {
  dim3 grid(N / 128, M / 128);
  mfma_gemm<BIAS><<<grid, 256, 0, s>>>(A, Bt, bias, C, M, N, K);
}

// ---------------- pre-cast kernels ----------------
// gathered bf16 A: out[m][k] for k<900: emb[ids[m*3+k/300]*300 + k%300]; else 0
__global__ __launch_bounds__(256) void gather_bf16_k(
    const int* __restrict__ ids, const float* __restrict__ emb,
    ushort_t* __restrict__ outp) {
  const int m = blockIdx.x, t = threadIdx.x;
  if (t >= KP / 4) return;
  const int k = t * 4;
  ushort4 o = make_ushort4(0, 0, 0, 0);
  if (k < KIN) {
    const int node = (k >= 600) ? 2 : ((k >= 300) ? 1 : 0);
    const int off = k - node * 300;  // %4==0, <=296: float4 never straddles
    const int id = ids[m * 3 + node];
    float4 v = *(const float4*)(emb + (size_t)id * 300 + off);
    o = make_ushort4(f2bf(v.x), f2bf(v.y), f2bf(v.z), f2bf(v.w));
  }
  *(ushort4*)(outp + (size_t)m * KP + k) = o;
}

// src [R][Cc] f32 -> dst [Cc][Rp] bf16 transposed; dst[c][r]=src[r][c], 0 if r>=R
__global__ __launch_bounds__(256) void transpose_cast_k(
    const float* __restrict__ src, ushort_t* __restrict__ dst,
    int R, int Cc, int Rp) {
  __shared__ float t[32][33];
  const int tx = threadIdx.x & 31, ty = threadIdx.x >> 5;
  const int r0 = blockIdx.y * 32, c0 = blockIdx.x * 32;
#pragma unroll
  for (int i = 0; i < 4; ++i) {
    int r = r0 + ty + i * 8, c = c0 + tx;
    t[ty + i * 8][tx] = (r < R && c < Cc) ? src[(size_t)r * Cc + c] : 0.f;
  }
  __syncthreads();
#pragma unroll
  for (int i = 0; i < 4; ++i) {
    int c = c0 + ty + i * 8, r = r0 + tx;
    if (c < Cc && r < Rp) dst[(size_t)c * Rp + r] = f2bf(t[tx][ty + i * 8]);
  }
}

// src [R][C] f32 -> dst [R][Cp] bf16 (pad cols with 0); C%4==0, Cp%4==0
__global__ __launch_bounds__(128) void cast_pad_rows_k(
    const float* __restrict__ src, ushort_t* __restrict__ dst, int C, int Cp) {
  const int r = blockIdx.x, t = threadIdx.x;
  const int k = t * 4;
  if (k >= Cp) return;
  ushort4 o = make_ushort4(0, 0, 0, 0);
  if (k < C) {
    float4 v = *(const float4*)(src + (size_t)r * C + k);
    o = make_ushort4(f2bf(v.x), f2bf(v.y), f2bf(v.z), f2bf(v.w));
  }
  *(ushort4*)(dst + (size_t)r * Cp + k) = o;
}

// ---------------- fp32 tiled GEMM (small tail mats) ----------------
template <int CH, int TRANSB, int RELU, int BIAS>
__global__ __launch_bounds__(256) void gemm_k(
    const float* __restrict__ A, const float* __restrict__ B,
    const float* __restrict__ bias, float* __restrict__ C,
    int M, int N, int K) {
  constexpr int BMv = 64 * CH, BNv = 64 * CH, BKv = 16;
  constexpr int LDA = BMv + 4, LDB = BNv + 4;
  __shared__ float As[BKv][LDA];
  __shared__ float Bs[BKv][LDB];
  const int tid = threadIdx.x;
  const int tx = tid & 15, ty = tid >> 4;
  const int row0 = blockIdx.y * BMv, col0 = blockIdx.x * BNv;
  float acc[CH][CH][4][4] = {};

  for (int k0 = 0; k0 < K; k0 += BKv) {
#pragma unroll
    for (int l = 0; l < CH; ++l) {
      int e = tid + l * 256;
      int m = e >> 2;
      int kk = (e & 3) * 4;
      int gr = row0 + m, gk = k0 + kk;
      float4 v = make_float4(0.f, 0.f, 0.f, 0.f);
      if (gr < M && gk < K) v = *(const float4*)(A + (size_t)gr * K + gk);
      As[kk + 0][m] = v.x;
      As[kk + 1][m] = v.y;
      As[kk + 2][m] = v.z;
      As[kk + 3][m] = v.w;
    }
    if (TRANSB) {
#pragma unroll
      for (int l = 0; l < CH; ++l) {
        int e = tid + l * 256;
        int n = e >> 2;
        int kk = (e & 3) * 4;
        int gc = col0 + n, gk = k0 + kk;
        float4 v = make_float4(0.f, 0.f, 0.f, 0.f);
        if (gc < N && gk < K) v = *(const float4*)(B + (size_t)gc * K + gk);
        Bs[kk + 0][n] = v.x;
        Bs[kk + 1][n] = v.y;
        Bs[kk + 2][n] = v.z;
        Bs[kk + 3][n] = v.w;
      }
    } else {
#pragma unroll
      for (int l = 0; l < CH; ++l) {
        int e = tid + l * 256;
        int kk = e / (BNv / 4);
        int n = (e % (BNv / 4)) * 4;
        int gk = k0 + kk, gc = col0 + n;
        float4 v = make_float4(0.f, 0.f, 0.f, 0.f);
        if (gk < K && gc < N) v = *(const float4*)(B + (size_t)gk * N + gc);
        *(float4*)&Bs[kk][n] = v;
      }
    }
    __syncthreads();
#pragma unroll
    for (int kk = 0; kk < BKv; ++kk) {
      float a[CH][4], b[CH][4];
#pragma unroll
      for (int c = 0; c < CH; ++c) {
        float4 t = *(const float4*)&As[kk][c * 64 + ty * 4];
        a[c][0] = t.x; a[c][1] = t.y; a[c][2] = t.z; a[c][3] = t.w;
      }
#pragma unroll
      for (int c = 0; c < CH; ++c) {
        float4 t = *(const float4*)&Bs[kk][c * 64 + tx * 4];
        b[c][0] = t.x; b[c][1] = t.y; b[c][2] = t.z; b[c][3] = t.w;
      }
#pragma unroll
      for (int ci = 0; ci < CH; ++ci)
#pragma unroll
        for (int cj = 0; cj < CH; ++cj)
#pragma unroll
          for (int i = 0; i < 4; ++i)
#pragma unroll
            for (int j = 0; j < 4; ++j)
              acc[ci][cj][i][j] += a[ci][i] * b[cj][j];
    }
    __syncthreads();
  }

#pragma unroll
  for (int ci = 0; ci < CH; ++ci)
#pragma unroll
    for (int i = 0; i < 4; ++i) {
      int r = row0 + ci * 64 + ty * 4 + i;
      if (r >= M) continue;
#pragma unroll
      for (int cj = 0; cj < CH; ++cj) {
        int cl = col0 + cj * 64 + tx * 4;
        if (cl >= N) continue;
        float4 v = make_float4(acc[ci][cj][i][0], acc[ci][cj][i][1],
                               acc[ci][cj][i][2], acc[ci][cj][i][3]);
        if (BIAS) {
          float4 bb = *(const float4*)(bias + cl);
          v.x += bb.x; v.y += bb.y; v.z += bb.z; v.w += bb.w;
        }
        if (RELU) {
          v.x = fmaxf(v.x, 0.f); v.y = fmaxf(v.y, 0.f);
          v.z = fmaxf(v.z, 0.f); v.w = fmaxf(v.w, 0.f);
        }
        *(float4*)(C + (size_t)r * N + cl) = v;
      }
    }
}

template <int CH, int TRANSB, int RELU, int BIAS>
static void launch_gemm(const float* A, const float* Bm, const float* bias,
                        float* C, int M, int N, int K, hipStream_t stream) {
  constexpr int BMv = 64 * CH, BNv = 64 * CH;
  dim3 grid((N + BNv - 1) / BNv, (M + BMv - 1) / BMv);
  gemm_k<CH, TRANSB, RELU, BIAS><<<grid, 256, 0, stream>>>(A, Bm, bias, C, M, N, K);
}

// ---------------- hyperbolic row ops ----------------
__global__ __launch_bounds__(256) void expproj_kernel(
    const float* __restrict__ in, float* __restrict__ outp, int D,
    const float* __restrict__ curv, int ci) {
  const int row = blockIdx.x, tid = threadIdx.x;
  const float* x = in + (size_t)row * D;
  float* y = outp + (size_t)row * D;
  const float c = curv[ci];
  const float Kc = 1.f / c, sqrtK = sqrtf(Kc);
  float ss = 0.f;
  for (int d = 1 + tid; d < D; d += 256) {
    float v = x[d];
    ss += v * v;
  }
  ss = blockReduceSum256(ss);
  float n = fmaxf(sqrtf(ss), 1e-15f);
  float theta = n / sqrtK;
  float f = sqrtK * sinhf(theta) / n;
  float ss2 = f * f * ss;
  float first = sqrtf(fmaxf(Kc + ss2, 1e-7f));
  if (tid == 0) y[0] = first;
  for (int d = 1 + tid; d < D; d += 256) y[d] = f * x[d];
}

// out = proj_tan0(logmap0(in, c)); optional bf16 copy
__global__ __launch_bounds__(256) void logmap_kernel(
    const float* __restrict__ in, float* __restrict__ outp,
    ushort_t* __restrict__ outb, int D,
    const float* __restrict__ curv, int ci) {
  const int row = blockIdx.x, tid = threadIdx.x;
  const float* x = in + (size_t)row * D;
  float* y = outp + (size_t)row * D;
  const float c = curv[ci];
  const float Kc = 1.f / c, sqrtK = sqrtf(Kc);
  float x0 = x[0];
  float ss = 0.f;
  for (int d = 1 + tid; d < D; d += 256) {
    float v = x[d];
    ss += v * v;
  }
  ss = blockReduceSum256(ss);
  float n = fmaxf(sqrtf(ss), 1e-15f);
  float theta = fmaxf(x0 / sqrtK, 1.f + 1e-7f);
  float r = sqrtK * acoshf(theta) / n;
  if (tid == 0) {
    y[0] = 0.f;
    if (outb) outb[(size_t)row * D] = 0;
  }
  for (int d = 1 + tid; d < D; d += 256) {
    float v = r * x[d];
    y[d] = v;
    if (outb) outb[(size_t)row * D + d] = f2bf(v);
  }
}

// ---------------- attention ----------------
__global__ __launch_bounds__(256) void s_kernel(
    const float* __restrict__ kp, const float* __restrict__ qp,
    float* __restrict__ S) {
  const int b = blockIdx.y, kr = blockIdx.x;
  __shared__ float kps[HID];
  __shared__ float red[8][33];
  const int tid = threadIdx.x;
  const float* kpr = kp + ((size_t)b * NK + kr) * HID;
  for (int d = tid; d < HID; d += 256) kps[d] = kpr[d];
  __syncthreads();
  const int q = tid & 31, g = tid >> 5;
  float part = 0.f;
  if (q < NQ) {
    const float4* qpr = (const float4*)(qp + ((size_t)b * NQ + q) * HID + g * 64);
#pragma unroll
    for (int i = 0; i < 16; ++i) {
      float4 v = qpr[i];
      part += kps[g * 64 + i * 4 + 0] * v.x + kps[g * 64 + i * 4 + 1] * v.y +
              kps[g * 64 + i * 4 + 2] * v.z + kps[g * 64 + i * 4 + 3] * v.w;
    }
  }
  red[g][q] = part;
  __syncthreads();
  if (tid < NQ) {
    float s = 0.f;
#pragma unroll
    for (int g2 = 0; g2 < 8; ++g2) s += red[g2][tid];
    S[((size_t)b * NK + kr) * NQ + tid] = s * 0.044194173824159216f;
  }
}

// att_k: grid (4, BATCH); each block does 25 k-rows of one batch
__global__ __launch_bounds__(256) void attk_kernel(
    const float* __restrict__ S, const float* __restrict__ qt,
    const float* __restrict__ kt, float* __restrict__ outp) {
  const int b = blockIdx.y, tid = threadIdx.x;
  const int kr0 = blockIdx.x * 25;
  __shared__ float qts[NQ * HID];  // 60 KB
  __shared__ float P[32];
  const float* qtb = qt + (size_t)b * NQ * HID;
  for (int e = tid; e < NQ * HID; e += 256) qts[e] = qtb[e];
  __syncthreads();
  for (int kr = kr0; kr < kr0 + 25; ++kr) {
    if (tid < 32) {
      float v = (tid < NQ) ? S[((size_t)b * NK + kr) * NQ + tid] : -1e30f;
      float m = v;
#pragma unroll
      for (int o = 16; o > 0; o >>= 1) m = fmaxf(m, __shfl_xor(m, o, 32));
      float e = (tid < NQ) ? expf(v - m) : 0.f;
      float ssum = e;
#pragma unroll
      for (int o = 16; o > 0; o >>= 1) ssum += __shfl_xor(ssum, o, 32);
      if (tid < NQ) P[tid] = e / ssum;
    }
    __syncthreads();
    const size_t base = ((size_t)b * NK + kr) * HID;
    float acc0 = kt[base + tid];
    float acc1 = kt[base + tid + 256];
#pragma unroll
    for (int q = 0; q < NQ; ++q) {
      float p = P[q];
      acc0 += p * qts[q * HID + tid];
      acc1 += p * qts[q * HID + tid + 256];
    }
    outp[base + tid] = acc0;
    outp[base + tid + 256] = acc1;
    __syncthreads();
  }
}

__global__ __launch_bounds__(256) void attq_kernel(
    const float* __restrict__ S, const float* __restrict__ kt,
    const float* __restrict__ qt, float* __restrict__ outp) {
  const int b = blockIdx.y, qr = blockIdx.x;
  const int tid = threadIdx.x;
  __shared__ float P[128];
  float v = (tid < NK) ? S[((size_t)b * NK + tid) * NQ + qr] : -1e30f;
  float m = blockReduceMax256(v);
  float e = (tid < NK) ? expf(v - m) : 0.f;
  float s = blockReduceSum256(e);
  if (tid < NK) P[tid] = e / s;
  __syncthreads();
  const size_t qbase = ((size_t)b * NQ + qr) * HID;
  float acc0 = qt[qbase + tid];
  float acc1 = qt[qbase + tid + 256];
  for (int kr = 0; kr < NK; ++kr) {
    float p = P[kr];
    const size_t kbase = ((size_t)b * NK + kr) * HID;
    acc0 += p * kt[kbase + tid];
    acc1 += p * kt[kbase + tid + 256];
  }
  outp[qbase + tid] = acc0;
  outp[qbase + tid + 256] = acc1;
}

// ---------------- tail ----------------
__global__ __launch_bounds__(512) void mean_kernel(
    const float* __restrict__ kx, const float* __restrict__ qx,
    float* __restrict__ last) {
  const int b = blockIdx.x, tid = threadIdx.x;
  float sk = 0.f;
  for (int r = 0; r < NK; ++r) sk += kx[((size_t)b * NK + r) * HID + tid];
  float sq = 0.f;
  for (int r = 0; r < NQ; ++r) sq += qx[((size_t)b * NQ + r) * HID + tid];
  last[(size_t)b * 1024 + tid] = sk * (1.f / NK);
  last[(size_t)b * 1024 + HID + tid] = sq * (1.f / NQ);
}

__global__ __launch_bounds__(256) void logsoftmax_kernel(float* __restrict__ x, int N) {
  const int b = blockIdx.x, tid = threadIdx.x;
  float* row = x + (size_t)b * N;
  float m = -3.4e38f;
  for (int i = tid; i < N; i += 256) m = fmaxf(m, row[i]);
  m = blockReduceMax256(m);
  float s = 0.f;
  for (int i = tid; i < N; i += 256) s += expf(row[i] - m);
  s = blockReduceSum256(s);
  float lse = m + logf(s);
  for (int i = tid; i < N; i += 256) row[i] -= lse;
}

// ---------------- launch ----------------
extern "C" void kernel_launch(void* const* d_in, const int* in_sizes, int n_in,
                              void* d_out, int out_size, void* d_ws, size_t ws_size,
                              hipStream_t stream) {
  const int* qid = (const int*)d_in[0];
  const int* kid = (const int*)d_in[1];
  const float* emb = (const float*)d_in[2];
  const float* q2h_w = (const float*)d_in[3];
  const float* q2h_b = (const float*)d_in[4];
  const float* k2h_w = (const float*)d_in[5];
  const float* k2h_b = (const float*)d_in[6];
  const float* Wk = (const float*)d_in[7];
  const float* Wq = (const float*)d_in[8];
  const float* curv = (const float*)d_in[9];
  const float* p1w = (const float*)d_in[10];
  const float* p1b = (const float*)d_in[11];
  const float* p2w = (const float*)d_in[12];
  const float* p2b = (const float*)d_in[13];
  const float* glove = (const float*)d_in[14];
  float* out = (float*)d_out;
  float* ws = (float*)d_ws;

  const int MK = BATCH * NK;  // 25600
  const int MQ = BATCH * NQ;  // 7680

  // fp32 region
  float* Xk = ws;                              // 25600*512
  float* Ak = Xk + (size_t)MK * HID;           // 25600*512
  float* Xq = Ak + (size_t)MK * HID;           // 7680*512
  float* Aq = Xq + (size_t)MQ * HID;           // 7680*512
  float* S = Aq + (size_t)MQ * HID;            // 256*100*30
  float* last = S + (size_t)BATCH * NK * NQ;   // 256*1024
  float* h1 = last + (size_t)BATCH * 1024;     // 256*512
  float* o2 = h1 + (size_t)BATCH * HID;        // 256*300
  float* fend = o2 + (size_t)BATCH * NOUT;

  // bf16 region (ushort)
  ushort_t* ub = (ushort_t*)fend;
  ushort_t* Akb = ub;                            // 25600*928 (dead after k2h gemm)
  ushort_t* Aqb = Akb + (size_t)MK * KP;         // 7680*928
  ushort_t* Xkb = Aqb + (size_t)MQ * KP;         // 25600*512
  ushort_t* Xqb = Xkb + (size_t)MK * HID;        // 7680*512
  ushort_t* q2h_wt = Xqb + (size_t)MQ * HID;     // 512*928
  ushort_t* k2h_wt = q2h_wt + (size_t)HID * KP;  // 512*928
  ushort_t* Wkt = k2h_wt + (size_t)HID * KP;     // 3*512*512
  ushort_t* Wqt = Wkt + (size_t)NLAYERS * HID * HID;
  ushort_t* o2b = Wqt + (size_t)NLAYERS * HID * HID;  // 256*320
  ushort_t* gloveb = Akb;  // overlay: built after k2h gemm, used at the end

  // ---- pre-casts ----
  gather_bf16_k<<<MQ, 256, 0, stream>>>(qid, emb, Aqb);
  gather_bf16_k<<<MK, 256, 0, stream>>>(kid, emb, Akb);
  transpose_cast_k<<<dim3(HID / 32, KP / 32), 256, 0, stream>>>(q2h_w, q2h_wt, KIN, HID, KP);
  transpose_cast_k<<<dim3(HID / 32, KP / 32), 256, 0, stream>>>(k2h_w, k2h_wt, KIN, HID, KP);
  for (int i = 0; i < NLAYERS; ++i) {
    transpose_cast_k<<<dim3(16, 16), 256, 0, stream>>>(
        Wk + (size_t)i * HID * HID, Wkt + (size_t)i * HID * HID, HID, HID, HID);
    transpose_cast_k<<<dim3(16, 16), 256, 0, stream>>>(
        Wq + (size_t)i * HID * HID, Wqt + (size_t)i * HID * HID, HID, HID, HID);
  }

  // ---- input projections (bf16 MFMA) ----
  launch_mfma<1>(Aqb, q2h_wt, q2h_b, Xq, MQ, HID, KP, stream);
  launch_mfma<1>(Akb, k2h_wt, k2h_b, Xk, MK, HID, KP, stream);

  // glove cast (overlays Akb, which is now dead)
  cast_pad_rows_k<<<NANS, 128, 0, stream>>>(glove, gloveb, NOUT, 320);

  // ---- initial hyperbolic embedding ----
  expproj_kernel<<<MQ, 256, 0, stream>>>(Xq, Xq, HID, curv, 0);
  expproj_kernel<<<MK, 256, 0, stream>>>(Xk, Xk, HID, curv, 0);

  for (int i = 0; i < NLAYERS; ++i) {
    logmap_kernel<<<MK, 256, 0, stream>>>(Xk, Xk, Xkb, HID, curv, i);
    logmap_kernel<<<MQ, 256, 0, stream>>>(Xq, Xq, Xqb, HID, curv, i);
    launch_mfma<0>(Xkb, Wkt + (size_t)i * HID * HID, nullptr, Ak, MK, HID, HID, stream);
    launch_mfma<0>(Xqb, Wqt + (size_t)i * HID * HID, nullptr, Aq, MQ, HID, HID, stream);
    s_kernel<<<dim3(NK, BATCH), 256, 0, stream>>>(Ak, Aq, S);
    attk_kernel<<<dim3(4, BATCH), 256, 0, stream>>>(S, Xq, Xk, Ak);
    attq_kernel<<<dim3(NQ, BATCH), 256, 0, stream>>>(S, Xk, Xq, Aq);
    expproj_kernel<<<MK, 256, 0, stream>>>(Ak, Xk, HID, curv, i + 1);
    expproj_kernel<<<MQ, 256, 0, stream>>>(Aq, Xq, HID, curv, i + 1);
  }

  mean_kernel<<<BATCH, 512, 0, stream>>>(Xk, Xq, last);
  logmap_kernel<<<BATCH, 256, 0, stream>>>(last, last, nullptr, 1024, curv, NLAYERS);
  launch_gemm<1, 0, 1, 1>(last, p1w, p1b, h1, BATCH, HID, 1024, stream);
  launch_gemm<1, 0, 0, 1>(h1, p2w, p2b, o2, BATCH, NOUT, HID, stream);
  cast_pad_rows_k<<<BATCH, 128, 0, stream>>>(o2, o2b, NOUT, 320);
  launch_mfma<0>(o2b, gloveb, nullptr, out, BATCH, NANS, 320, stream);
  logsoftmax_kernel<<<BATCH, 256, 0, stream>>>(out, NANS);
}

// Round 4
// 957.294 us; speedup vs baseline: 4.5647x; 2.0644x over previous
//
#include <hip/hip_runtime.h>
#include <math.h>

// Problem constants (from setup_inputs)
#define BATCH 256
#define NQ 30
#define NK 100
#define HID 512
#define WORD 300
#define KIN 900          // WORD*3
#define KP 928           // KIN padded to multiple of 32
#define NANS 32000
#define NOUT 300
#define NLAYERS 3
#define SCALE 0.044194173824159216f  // 1/sqrt(512)

typedef __attribute__((ext_vector_type(8))) short bf16x8;
typedef __attribute__((ext_vector_type(4))) float f32x4;
typedef unsigned short ushort_t;

__device__ __forceinline__ unsigned short f2bf(float f) {
  unsigned int u = __float_as_uint(f);
  u = (u + 0x7FFF + ((u >> 16) & 1)) >> 16;  // RNE
  return (unsigned short)u;
}
__device__ __forceinline__ float bf2f(unsigned short s) {
  return __uint_as_float(((unsigned int)s) << 16);
}

typedef const __attribute__((address_space(1))) unsigned int* gas_u32;
typedef __attribute__((address_space(3))) unsigned int* las_u32;
__device__ __forceinline__ void gld_lds16(const void* g, void* l) {
  __builtin_amdgcn_global_load_lds((gas_u32)g, (las_u32)l, 16, 0, 0);
}

// ---------------- reduction helpers ----------------
__device__ __forceinline__ float waveReduceSum(float v) {
#pragma unroll
  for (int o = 32; o > 0; o >>= 1) v += __shfl_xor(v, o);
  return v;
}
__device__ __forceinline__ float waveReduceMax(float v) {
#pragma unroll
  for (int o = 32; o > 0; o >>= 1) v = fmaxf(v, __shfl_xor(v, o));
  return v;
}
__device__ float blockReduceSum256(float v) {
  __shared__ float sm[4];
  int lane = threadIdx.x & 63, w = threadIdx.x >> 6;
  v = waveReduceSum(v);
  if (lane == 0) sm[w] = v;
  __syncthreads();
  float r = sm[0] + sm[1] + sm[2] + sm[3];
  __syncthreads();
  return r;
}
__device__ float blockReduceMax256(float v) {
  __shared__ float sm[4];
  int lane = threadIdx.x & 63, w = threadIdx.x >> 6;
  v = waveReduceMax(v);
  if (lane == 0) sm[w] = v;
  __syncthreads();
  float r = fmaxf(fmaxf(sm[0], sm[1]), fmaxf(sm[2], sm[3]));
  __syncthreads();
  return r;
}

// ---------------- bf16 MFMA GEMM ----------------
// C[M,N] = A[M,K](bf16) @ Bt[N,K]^T(bf16) (+bias). Outputs: f32 C and/or bf16 Cb.
// ZC0: force column 0 of output to 0 (proj_tan0 fused).
// M%128==0, N%128==0, K%32==0. 4 waves, 128x128 tile, BK=32.
template <int BIAS, int OUTF32, int OUTBF16, int ZC0>
__global__ __launch_bounds__(256) void mfma_gemm(
    const ushort_t* __restrict__ A, const ushort_t* __restrict__ Bt,
    const float* __restrict__ bias, float* __restrict__ C,
    ushort_t* __restrict__ Cb, int M, int N, int K) {
  __shared__ __align__(16) ushort_t Abuf[128 * 32];
  __shared__ __align__(16) ushort_t Bbuf[128 * 32];
  const int tid = threadIdx.x;
  const int lane = tid & 63, w = tid >> 6;
  const int wr = w >> 1, wc = w & 1;
  const int row0 = blockIdx.y * 128, col0 = blockIdx.x * 128;
  const int s_r = lane & 15, s_kq = lane >> 4;

  const size_t a_src0 = (size_t)(row0 + (w * 2 + 0) * 16 + s_r) * K + s_kq * 8;
  const size_t a_src1 = (size_t)(row0 + (w * 2 + 1) * 16 + s_r) * K + s_kq * 8;
  const size_t b_src0 = (size_t)(col0 + (w * 2 + 0) * 16 + s_r) * K + s_kq * 8;
  const size_t b_src1 = (size_t)(col0 + (w * 2 + 1) * 16 + s_r) * K + s_kq * 8;
  ushort_t* a_dst0 = Abuf + (w * 2 + 0) * 512;
  ushort_t* a_dst1 = Abuf + (w * 2 + 1) * 512;
  ushort_t* b_dst0 = Bbuf + (w * 2 + 0) * 512;
  ushort_t* b_dst1 = Bbuf + (w * 2 + 1) * 512;

  f32x4 acc[4][4];
#pragma unroll
  for (int i = 0; i < 4; ++i)
#pragma unroll
    for (int j = 0; j < 4; ++j) acc[i][j] = (f32x4){0.f, 0.f, 0.f, 0.f};

  for (int k0 = 0; k0 < K; k0 += 32) {
    gld_lds16(A + a_src0 + k0, a_dst0);
    gld_lds16(A + a_src1 + k0, a_dst1);
    gld_lds16(Bt + b_src0 + k0, b_dst0);
    gld_lds16(Bt + b_src1 + k0, b_dst1);
    __syncthreads();
    bf16x8 af[4], bfr[4];
#pragma unroll
    for (int mi = 0; mi < 4; ++mi)
      af[mi] = *(const bf16x8*)(Abuf + (wr * 4 + mi) * 512 + lane * 8);
#pragma unroll
    for (int nj = 0; nj < 4; ++nj)
      bfr[nj] = *(const bf16x8*)(Bbuf + (wc * 4 + nj) * 512 + lane * 8);
#pragma unroll
    for (int mi = 0; mi < 4; ++mi)
#pragma unroll
      for (int nj = 0; nj < 4; ++nj)
        acc[mi][nj] = __builtin_amdgcn_mfma_f32_16x16x32_bf16(
            af[mi], bfr[nj], acc[mi][nj], 0, 0, 0);
    __syncthreads();
  }

#pragma unroll
  for (int nj = 0; nj < 4; ++nj) {
    const int n = col0 + wc * 64 + nj * 16 + (lane & 15);
    const float bb = BIAS ? bias[n] : 0.f;
#pragma unroll
    for (int mi = 0; mi < 4; ++mi) {
      f32x4 v = acc[mi][nj];
#pragma unroll
      for (int r = 0; r < 4; ++r) {
        const int m = row0 + wr * 64 + mi * 16 + (lane >> 4) * 4 + r;
        float val = v[r] + bb;
        if (ZC0 && n == 0) val = 0.f;
        if (OUTF32) C[(size_t)m * N + n] = val;
        if (OUTBF16) Cb[(size_t)m * N + n] = f2bf(val);
      }
    }
  }
}

template <int BIAS, int OUTF32, int OUTBF16, int ZC0>
static void launch_mfma(const ushort_t* A, const ushort_t* Bt, const float* bias,
                        float* C, ushort_t* Cb, int M, int N, int K, hipStream_t s) {
  dim3 grid(N / 128, M / 128);
  mfma_gemm<BIAS, OUTF32, OUTBF16, ZC0><<<grid, 256, 0, s>>>(A, Bt, bias, C, Cb, M, N, K);
}

// ---------------- pre-cast kernels ----------------
__global__ __launch_bounds__(256) void gather_bf16_k(
    const int* __restrict__ ids, const float* __restrict__ emb,
    ushort_t* __restrict__ outp) {
  const int m = blockIdx.x, t = threadIdx.x;
  if (t >= KP / 4) return;
  const int k = t * 4;
  ushort4 o = make_ushort4(0, 0, 0, 0);
  if (k < KIN) {
    const int node = (k >= 600) ? 2 : ((k >= 300) ? 1 : 0);
    const int off = k - node * 300;
    const int id = ids[m * 3 + node];
    float4 v = *(const float4*)(emb + (size_t)id * 300 + off);
    if (v.x != v.x) v.x = 0.f;
    if (v.y != v.y) v.y = 0.f;
    if (v.z != v.z) v.z = 0.f;
    if (v.w != v.w) v.w = 0.f;
    o = make_ushort4(f2bf(v.x), f2bf(v.y), f2bf(v.z), f2bf(v.w));
  }
  *(ushort4*)(outp + (size_t)m * KP + k) = o;
}

// src [R][Cc] f32 -> dst [Cc][Rp] bf16 transposed (pad r>=R with 0)
__global__ __launch_bounds__(256) void transpose_cast_k(
    const float* __restrict__ src, ushort_t* __restrict__ dst,
    int R, int Cc, int Rp) {
  __shared__ float t[32][33];
  const int tx = threadIdx.x & 31, ty = threadIdx.x >> 5;
  const int r0 = blockIdx.y * 32, c0 = blockIdx.x * 32;
#pragma unroll
  for (int i = 0; i < 4; ++i) {
    int r = r0 + ty + i * 8, c = c0 + tx;
    t[ty + i * 8][tx] = (r < R && c < Cc) ? src[(size_t)r * Cc + c] : 0.f;
  }
  __syncthreads();
#pragma unroll
  for (int i = 0; i < 4; ++i) {
    int c = c0 + ty + i * 8, r = r0 + tx;
    if (c < Cc && r < Rp) dst[(size_t)c * Rp + r] = f2bf(t[tx][ty + i * 8]);
  }
}

// src [R][C] f32 -> dst [R][Cp] bf16 (pad cols with 0)
__global__ __launch_bounds__(128) void cast_pad_rows_k(
    const float* __restrict__ src, ushort_t* __restrict__ dst, int C, int Cp) {
  const int r = blockIdx.x, t = threadIdx.x;
  const int k = t * 4;
  if (k >= Cp) return;
  ushort4 o = make_ushort4(0, 0, 0, 0);
  if (k < C) {
    float4 v = *(const float4*)(src + (size_t)r * C + k);
    o = make_ushort4(f2bf(v.x), f2bf(v.y), f2bf(v.z), f2bf(v.w));
  }
  *(ushort4*)(dst + (size_t)r * Cp + k) = o;
}

// ---------------- fp32 tiled GEMM (small tail mats) ----------------
template <int CH, int TRANSB, int RELU, int BIAS>
__global__ __launch_bounds__(256) void gemm_k(
    const float* __restrict__ A, const float* __restrict__ B,
    const float* __restrict__ bias, float* __restrict__ C,
    int M, int N, int K) {
  constexpr int BMv = 64 * CH, BNv = 64 * CH, BKv = 16;
  constexpr int LDA = BMv + 4, LDB = BNv + 4;
  __shared__ float As[BKv][LDA];
  __shared__ float Bs[BKv][LDB];
  const int tid = threadIdx.x;
  const int tx = tid & 15, ty = tid >> 4;
  const int row0 = blockIdx.y * BMv, col0 = blockIdx.x * BNv;
  float acc[CH][CH][4][4] = {};

  for (int k0 = 0; k0 < K; k0 += BKv) {
#pragma unroll
    for (int l = 0; l < CH; ++l) {
      int e = tid + l * 256;
      int m = e >> 2;
      int kk = (e & 3) * 4;
      int gr = row0 + m, gk = k0 + kk;
      float4 v = make_float4(0.f, 0.f, 0.f, 0.f);
      if (gr < M && gk < K) v = *(const float4*)(A + (size_t)gr * K + gk);
      As[kk + 0][m] = v.x;
      As[kk + 1][m] = v.y;
      As[kk + 2][m] = v.z;
      As[kk + 3][m] = v.w;
    }
    if (TRANSB) {
#pragma unroll
      for (int l = 0; l < CH; ++l) {
        int e = tid + l * 256;
        int n = e >> 2;
        int kk = (e & 3) * 4;
        int gc = col0 + n, gk = k0 + kk;
        float4 v = make_float4(0.f, 0.f, 0.f, 0.f);
        if (gc < N && gk < K) v = *(const float4*)(B + (size_t)gc * K + gk);
        Bs[kk + 0][n] = v.x;
        Bs[kk + 1][n] = v.y;
        Bs[kk + 2][n] = v.z;
        Bs[kk + 3][n] = v.w;
      }
    } else {
#pragma unroll
      for (int l = 0; l < CH; ++l) {
        int e = tid + l * 256;
        int kk = e / (BNv / 4);
        int n = (e % (BNv / 4)) * 4;
        int gk = k0 + kk, gc = col0 + n;
        float4 v = make_float4(0.f, 0.f, 0.f, 0.f);
        if (gk < K && gc < N) v = *(const float4*)(B + (size_t)gk * N + gc);
        *(float4*)&Bs[kk][n] = v;
      }
    }
    __syncthreads();
#pragma unroll
    for (int kk = 0; kk < BKv; ++kk) {
      float a[CH][4], b[CH][4];
#pragma unroll
      for (int c = 0; c < CH; ++c) {
        float4 t = *(const float4*)&As[kk][c * 64 + ty * 4];
        a[c][0] = t.x; a[c][1] = t.y; a[c][2] = t.z; a[c][3] = t.w;
      }
#pragma unroll
      for (int c = 0; c < CH; ++c) {
        float4 t = *(const float4*)&Bs[kk][c * 64 + tx * 4];
        b[c][0] = t.x; b[c][1] = t.y; b[c][2] = t.z; b[c][3] = t.w;
      }
#pragma unroll
      for (int ci = 0; ci < CH; ++ci)
#pragma unroll
        for (int cj = 0; cj < CH; ++cj)
#pragma unroll
          for (int i = 0; i < 4; ++i)
#pragma unroll
            for (int j = 0; j < 4; ++j)
              acc[ci][cj][i][j] += a[ci][i] * b[cj][j];
    }
    __syncthreads();
  }

#pragma unroll
  for (int ci = 0; ci < CH; ++ci)
#pragma unroll
    for (int i = 0; i < 4; ++i) {
      int r = row0 + ci * 64 + ty * 4 + i;
      if (r >= M) continue;
#pragma unroll
      for (int cj = 0; cj < CH; ++cj) {
        int cl = col0 + cj * 64 + tx * 4;
        if (cl >= N) continue;
        float4 v = make_float4(acc[ci][cj][i][0], acc[ci][cj][i][1],
                               acc[ci][cj][i][2], acc[ci][cj][i][3]);
        if (BIAS) {
          float4 bb = *(const float4*)(bias + cl);
          v.x += bb.x; v.y += bb.y; v.z += bb.z; v.w += bb.w;
        }
        if (RELU) {
          v.x = fmaxf(v.x, 0.f); v.y = fmaxf(v.y, 0.f);
          v.z = fmaxf(v.z, 0.f); v.w = fmaxf(v.w, 0.f);
        }
        *(float4*)(C + (size_t)r * N + cl) = v;
      }
    }
}

template <int CH, int TRANSB, int RELU, int BIAS>
static void launch_gemm(const float* A, const float* Bm, const float* bias,
                        float* C, int M, int N, int K, hipStream_t stream) {
  constexpr int BMv = 64 * CH, BNv = 64 * CH;
  dim3 grid((N + BNv - 1) / BNv, (M + BMv - 1) / BMv);
  gemm_k<CH, TRANSB, RELU, BIAS><<<grid, 256, 0, stream>>>(A, Bm, bias, C, M, N, K);
}

// ---------------- hyperbolic row ops (only at the boundary now) ------------
// in-place: x -> proj(expmap0(proj_tan0(x), c), c)
__global__ __launch_bounds__(256) void expproj_kernel(
    float* __restrict__ x_, int D, const float* __restrict__ curv, int ci) {
  const int row = blockIdx.x, tid = threadIdx.x;
  float* x = x_ + (size_t)row * D;
  const float c = curv[ci];
  const float Kc = 1.f / c, sqrtK = sqrtf(Kc);
  float ss = 0.f;
  for (int d = 1 + tid; d < D; d += 256) {
    float v = x[d];
    ss += v * v;
  }
  ss = blockReduceSum256(ss);
  float n = fmaxf(sqrtf(ss), 1e-15f);
  float theta = n / sqrtK;
  float f = sqrtK * sinhf(theta) / n;
  float ss2 = f * f * ss;
  float first = sqrtf(fmaxf(Kc + ss2, 1e-7f));
  for (int d = 1 + tid; d < D; d += 256) x[d] = f * x[d];
  if (tid == 0) x[0] = first;
}

// out = proj_tan0(logmap0(in, c)) in place
__global__ __launch_bounds__(256) void logmap_kernel(
    float* __restrict__ x_, int D, const float* __restrict__ curv, int ci) {
  const int row = blockIdx.x, tid = threadIdx.x;
  float* x = x_ + (size_t)row * D;
  const float c = curv[ci];
  const float Kc = 1.f / c, sqrtK = sqrtf(Kc);
  float x0 = x[0];
  float ss = 0.f;
  for (int d = 1 + tid; d < D; d += 256) {
    float v = x[d];
    ss += v * v;
  }
  ss = blockReduceSum256(ss);
  float n = fmaxf(sqrtf(ss), 1e-15f);
  float theta = fmaxf(x0 / sqrtK, 1.f + 1e-7f);
  float r = sqrtK * acoshf(theta) / n;
  for (int d = 1 + tid; d < D; d += 256) x[d] = r * x[d];
  if (tid == 0) x[0] = 0.f;
}

// ---------------- attention ----------------
// S[b][kr][q] = SCALE * dot(kp[b,kr,:], qp[b,q,:]), bf16 operands via MFMA.
// Block = 1 batch, 7 waves; wave w does k-rows [w*16, w*16+16).
__global__ __launch_bounds__(448) void s2_kernel(
    const ushort_t* __restrict__ kp, const ushort_t* __restrict__ qp,
    float* __restrict__ S) {
  const int b = blockIdx.x;
  const int w = threadIdx.x >> 6, lane = threadIdx.x & 63;
  const int r = lane & 15, kq = lane >> 4;
  const ushort_t* kpb = kp + (size_t)b * NK * HID;
  const ushort_t* qpb = qp + (size_t)b * NQ * HID;
  const int arow = w * 16 + r;
  const int arow_c = (arow < NK) ? arow : (NK - 1);       // clamp (results discarded)
  const int brow1_c = (16 + r < NQ) ? (16 + r) : (NQ - 1);
  f32x4 acc0 = {0.f, 0.f, 0.f, 0.f}, acc1 = {0.f, 0.f, 0.f, 0.f};
  for (int k0 = 0; k0 < HID; k0 += 32) {
    bf16x8 af = *(const bf16x8*)(kpb + (size_t)arow_c * HID + k0 + kq * 8);
    bf16x8 b0 = *(const bf16x8*)(qpb + (size_t)r * HID + k0 + kq * 8);
    bf16x8 b1 = *(const bf16x8*)(qpb + (size_t)brow1_c * HID + k0 + kq * 8);
    acc0 = __builtin_amdgcn_mfma_f32_16x16x32_bf16(af, b0, acc0, 0, 0, 0);
    acc1 = __builtin_amdgcn_mfma_f32_16x16x32_bf16(af, b1, acc1, 0, 0, 0);
  }
  const int q0 = lane & 15;
  const int mbase = w * 16 + (lane >> 4) * 4;
#pragma unroll
  for (int rr = 0; rr < 4; ++rr) {
    const int m = mbase + rr;
    if (m < NK) {
      S[((size_t)b * NK + m) * NQ + q0] = acc0[rr] * SCALE;
      if (q0 + 16 < NQ)
        S[((size_t)b * NK + m) * NQ + q0 + 16] = acc1[rr] * SCALE;
    }
  }
}

// att_q = softmax_k(S^T) @ kt + qt. Block = 1 batch, 256 threads (float2 cols).
// Reads OLD Xk (kt) and OLD Xq (qt); writes Aq f32 + new qtb bf16.
__global__ __launch_bounds__(256) void attq2_kernel(
    const float* __restrict__ S, const float* __restrict__ Xk,
    const float* __restrict__ Xq, float* __restrict__ Aq,
    ushort_t* __restrict__ qtb_new) {
  const int b = blockIdx.x, tid = threadIdx.x;
  __shared__ float Ssm[NK][32];      // 12.8KB
  __shared__ float P[NQ][NK + 4];    // 12.5KB
  const float* Sb = S + (size_t)b * NK * NQ;
  for (int e = tid; e < NK * NQ; e += 256) Ssm[e / NQ][e % NQ] = Sb[e];
  __syncthreads();
  if (tid < NQ) {
    float m = -1e30f;
    for (int kr = 0; kr < NK; ++kr) m = fmaxf(m, Ssm[kr][tid]);
    float s = 0.f;
    for (int kr = 0; kr < NK; ++kr) {
      float e = expf(Ssm[kr][tid] - m);
      P[tid][kr] = e;
      s += e;
    }
    float inv = 1.f / s;
    for (int kr = 0; kr < NK; ++kr) P[tid][kr] *= inv;
  }
  __syncthreads();
  const float* ktb = Xk + (size_t)b * NK * HID;
  const float* qtb = Xq + (size_t)b * NQ * HID;
  float2 acc[15];
#pragma unroll 1
  for (int half = 0; half < 2; ++half) {
    const int qb = half * 15;
#pragma unroll
    for (int i = 0; i < 15; ++i) acc[i] = make_float2(0.f, 0.f);
    for (int kr = 0; kr < NK; ++kr) {
      float2 kv = *(const float2*)(ktb + (size_t)kr * HID + tid * 2);
#pragma unroll
      for (int i = 0; i < 15; ++i) {
        float p = P[qb + i][kr];
        acc[i].x += p * kv.x;
        acc[i].y += p * kv.y;
      }
    }
#pragma unroll
    for (int i = 0; i < 15; ++i) {
      const int q = qb + i;
      float2 res = *(const float2*)(qtb + (size_t)q * HID + tid * 2);
      float2 o = make_float2(acc[i].x + res.x, acc[i].y + res.y);
      *(float2*)(Aq + ((size_t)b * NQ + q) * HID + tid * 2) = o;
      ushort2 ob = make_ushort2(f2bf(o.x), f2bf(o.y));
      *(ushort2*)(qtb_new + ((size_t)b * NQ + q) * HID + tid * 2) = ob;
    }
  }
}

// att_k = softmax_q(S) @ qt + kt, IN PLACE on Xk/Xkb. Block = 1 batch, 512 thr.
// qt read from OLD Xqb (bf16) staged in LDS.
__global__ __launch_bounds__(512) void attk2_kernel(
    const float* __restrict__ S, const ushort_t* __restrict__ Xqb,
    float* __restrict__ Xk, ushort_t* __restrict__ Xkb) {
  const int b = blockIdx.x, tid = threadIdx.x;
  __shared__ __align__(16) ushort_t qts[NQ * HID];  // 30KB bf16
  __shared__ float P[NK][32];                       // 12.8KB
  const uint4* qsrc = (const uint4*)(Xqb + (size_t)b * NQ * HID);
  for (int e = tid; e < NQ * HID / 8; e += 512) ((uint4*)qts)[e] = qsrc[e];
  if (tid < NK) {
    const float* Srow = S + ((size_t)b * NK + tid) * NQ;
    float m = -1e30f;
    for (int q = 0; q < NQ; ++q) m = fmaxf(m, Srow[q]);
    float s = 0.f;
    for (int q = 0; q < NQ; ++q) {
      float e = expf(Srow[q] - m);
      P[tid][q] = e;
      s += e;
    }
    float inv = 1.f / s;
    for (int q = 0; q < NQ; ++q) P[tid][q] *= inv;
  }
  __syncthreads();
  float* ktb = Xk + (size_t)b * NK * HID;
  ushort_t* ktbb = Xkb + (size_t)b * NK * HID;
  const int c = tid;  // one column per thread
  for (int kr = 0; kr < NK; ++kr) {
    float acc = ktb[(size_t)kr * HID + c];
    for (int q = 0; q < NQ; ++q)
      acc += P[kr][q] * bf2f(qts[q * HID + c]);
    ktb[(size_t)kr * HID + c] = acc;
    ktbb[(size_t)kr * HID + c] = f2bf(acc);
  }
}

// ---------------- tail ----------------
__global__ __launch_bounds__(512) void mean_kernel(
    const float* __restrict__ kx, const float* __restrict__ qx,
    float* __restrict__ last) {
  const int b = blockIdx.x, tid = threadIdx.x;
  float sk = 0.f;
  for (int r = 0; r < NK; ++r) sk += kx[((size_t)b * NK + r) * HID + tid];
  float sq = 0.f;
  for (int r = 0; r < NQ; ++r) sq += qx[((size_t)b * NQ + r) * HID + tid];
  last[(size_t)b * 1024 + tid] = sk * (1.f / NK);
  last[(size_t)b * 1024 + HID + tid] = sq * (1.f / NQ);
}

__global__ __launch_bounds__(256) void logsoftmax_kernel(float* __restrict__ x, int N) {
  const int b = blockIdx.x, tid = threadIdx.x;
  float* row = x + (size_t)b * N;
  float m = -3.4e38f;
  for (int i = tid; i < N; i += 256) m = fmaxf(m, row[i]);
  m = blockReduceMax256(m);
  float s = 0.f;
  for (int i = tid; i < N; i += 256) s += expf(row[i] - m);
  s = blockReduceSum256(s);
  float lse = m + logf(s);
  for (int i = tid; i < N; i += 256) row[i] -= lse;
}

// ---------------- launch ----------------
extern "C" void kernel_launch(void* const* d_in, const int* in_sizes, int n_in,
                              void* d_out, int out_size, void* d_ws, size_t ws_size,
                              hipStream_t stream) {
  const int* qid = (const int*)d_in[0];
  const int* kid = (const int*)d_in[1];
  const float* emb = (const float*)d_in[2];
  const float* q2h_w = (const float*)d_in[3];
  const float* q2h_b = (const float*)d_in[4];
  const float* k2h_w = (const float*)d_in[5];
  const float* k2h_b = (const float*)d_in[6];
  const float* Wk = (const float*)d_in[7];
  const float* Wq = (const float*)d_in[8];
  const float* curv = (const float*)d_in[9];
  const float* p1w = (const float*)d_in[10];
  const float* p1b = (const float*)d_in[11];
  const float* p2w = (const float*)d_in[12];
  const float* p2b = (const float*)d_in[13];
  const float* glove = (const float*)d_in[14];
  float* out = (float*)d_out;

  const int MK = BATCH * NK;  // 25600
  const int MQ = BATCH * NQ;  // 7680

  // ---- workspace layout ----
  float* f = (float*)d_ws;
  float* Xk = f;                               // 25600*512 (kt, in-place updated)
  float* Xq0 = Xk + (size_t)MK * HID;          // 7680*512 (qt ping)
  float* Xq1 = Xq0 + (size_t)MQ * HID;         // 7680*512 (qt pong)
  float* S = Xq1 + (size_t)MQ * HID;           // 256*100*30
  float* last = S + (size_t)BATCH * NK * NQ;   // 256*1024
  float* h1 = last + (size_t)BATCH * 1024;     // 256*512
  float* o2 = h1 + (size_t)BATCH * HID;        // 256*300
  float* fend = o2 + (size_t)BATCH * NOUT;

  ushort_t* u = (ushort_t*)fend;
  ushort_t* gk = u;                            // 25600*928 (gather; later gloveb)
  ushort_t* gq = gk + (size_t)MK * KP;         // 7680*928
  ushort_t* Xkb = gq + (size_t)MQ * KP;        // 25600*512 (kt bf16, in-place)
  ushort_t* kpb = Xkb + (size_t)MK * HID;      // 25600*512 (kp scratch)
  ushort_t* qb0 = kpb + (size_t)MK * HID;      // 7680*512 (qt bf16 ping)
  ushort_t* qb1 = qb0 + (size_t)MQ * HID;      // 7680*512 (qp / qt bf16 pong)
  ushort_t* q2h_wt = qb1 + (size_t)MQ * HID;   // 512*928
  ushort_t* k2h_wt = q2h_wt + (size_t)HID * KP;
  ushort_t* Wkt = k2h_wt + (size_t)HID * KP;   // 3*512*512
  ushort_t* Wqt = Wkt + (size_t)NLAYERS * HID * HID;
  ushort_t* o2b = Wqt + (size_t)NLAYERS * HID * HID;  // 256*320
  ushort_t* gloveb = gk;  // overlay (gk dead after k2h GEMM)

  // ---- pre-casts ----
  gather_bf16_k<<<MQ, 256, 0, stream>>>(qid, emb, gq);
  gather_bf16_k<<<MK, 256, 0, stream>>>(kid, emb, gk);
  transpose_cast_k<<<dim3(HID / 32, KP / 32), 256, 0, stream>>>(q2h_w, q2h_wt, KIN, HID, KP);
  transpose_cast_k<<<dim3(HID / 32, KP / 32), 256, 0, stream>>>(k2h_w, k2h_wt, KIN, HID, KP);
  for (int i = 0; i < NLAYERS; ++i) {
    transpose_cast_k<<<dim3(16, 16), 256, 0, stream>>>(
        Wk + (size_t)i * HID * HID, Wkt + (size_t)i * HID * HID, HID, HID, HID);
    transpose_cast_k<<<dim3(16, 16), 256, 0, stream>>>(
        Wq + (size_t)i * HID * HID, Wqt + (size_t)i * HID * HID, HID, HID, HID);
  }

  // ---- input projections; fused proj_tan0 (col0=0): qt0/kt0 tangent vectors
  launch_mfma<1, 1, 1, 1>(gq, q2h_wt, q2h_b, Xq0, qb0, MQ, HID, KP, stream);
  launch_mfma<1, 1, 1, 1>(gk, k2h_wt, k2h_b, Xk, Xkb, MK, HID, KP, stream);

  // glove cast (overlays gk, now dead)
  cast_pad_rows_k<<<NANS, 128, 0, stream>>>(glove, gloveb, NOUT, 320);

  // ---- layers: tangent space only (exp/log roundtrip cancels; curv==const)
  float* Xq_cur = Xq0;
  float* Xq_alt = Xq1;
  ushort_t* Xqb_cur = qb0;
  ushort_t* Xqb_alt = qb1;
  for (int i = 0; i < NLAYERS; ++i) {
    // kp = kt@Wk, qp = qt@Wq  (bf16 outputs)
    launch_mfma<0, 0, 1, 0>(Xkb, Wkt + (size_t)i * HID * HID, nullptr, nullptr, kpb, MK, HID, HID, stream);
    launch_mfma<0, 0, 1, 0>(Xqb_cur, Wqt + (size_t)i * HID * HID, nullptr, nullptr, Xqb_alt, MQ, HID, HID, stream);
    // scores
    s2_kernel<<<BATCH, 448, 0, stream>>>(kpb, Xqb_alt, S);
    // att_q first (needs OLD kt); writes Xq_alt f32 + new qtb into Xqb_alt (qp dead)
    attq2_kernel<<<BATCH, 256, 0, stream>>>(S, Xk, Xq_cur, Xq_alt, Xqb_alt);
    // att_k (needs OLD qtb = Xqb_cur); updates Xk/Xkb in place
    attk2_kernel<<<BATCH, 512, 0, stream>>>(S, Xqb_cur, Xk, Xkb);
    // swap q buffers
    float* tf = Xq_cur; Xq_cur = Xq_alt; Xq_alt = tf;
    ushort_t* tu = Xqb_cur; Xqb_cur = Xqb_alt; Xqb_alt = tu;
  }

  // ---- boundary: to hyperbolic, mean, back to tangent ----
  expproj_kernel<<<MK, 256, 0, stream>>>(Xk, HID, curv, NLAYERS);
  expproj_kernel<<<MQ, 256, 0, stream>>>(Xq_cur, HID, curv, NLAYERS);
  mean_kernel<<<BATCH, 512, 0, stream>>>(Xk, Xq_cur, last);
  logmap_kernel<<<BATCH, 256, 0, stream>>>(last, 1024, curv, NLAYERS);

  // ---- head ----
  launch_gemm<1, 0, 1, 1>(last, p1w, p1b, h1, BATCH, HID, 1024, stream);
  launch_gemm<1, 0, 0, 1>(h1, p2w, p2b, o2, BATCH, NOUT, HID, stream);
  cast_pad_rows_k<<<BATCH, 128, 0, stream>>>(o2, o2b, NOUT, 320);
  launch_mfma<0, 1, 0, 0>(o2b, gloveb, nullptr, out, nullptr, BATCH, NANS, 320, stream);
  logsoftmax_kernel<<<BATCH, 256, 0, stream>>>(out, NANS);
}

// Round 5
// 816.381 us; speedup vs baseline: 5.3526x; 1.1726x over previous
//
#include <hip/hip_runtime.h>
#include <math.h>

// Problem constants (from setup_inputs)
#define BATCH 256
#define NQ 30
#define NK 100
#define HID 512
#define WORD 300
#define KIN 900          // WORD*3
#define KP 928           // KIN padded to multiple of 32
#define NANS 32000
#define NOUT 300
#define NOUTP 320        // NOUT padded to 32
#define NLAYERS 3
#define MQT (BATCH * NQ)   // 7680
#define MKT (BATCH * NK)   // 25600
#define SCALE 0.044194173824159216f  // 1/sqrt(512)

typedef __attribute__((ext_vector_type(8))) short bf16x8;
typedef __attribute__((ext_vector_type(4))) float f32x4;
typedef unsigned short ushort_t;

__device__ __forceinline__ unsigned short f2bf(float f) {
  unsigned int u = __float_as_uint(f);
  u = (u + 0x7FFF + ((u >> 16) & 1)) >> 16;  // RNE
  return (unsigned short)u;
}
__device__ __forceinline__ float bf2f(unsigned short s) {
  return __uint_as_float(((unsigned int)s) << 16);
}

typedef const __attribute__((address_space(1))) unsigned int* gas_u32;
typedef __attribute__((address_space(3))) unsigned int* las_u32;
__device__ __forceinline__ void gld_lds16(const void* g, void* l) {
  __builtin_amdgcn_global_load_lds((gas_u32)g, (las_u32)l, 16, 0, 0);
}

// ---------------- reduction helpers ----------------
__device__ __forceinline__ float waveReduceSum(float v) {
#pragma unroll
  for (int o = 32; o > 0; o >>= 1) v += __shfl_xor(v, o);
  return v;
}
__device__ __forceinline__ float waveReduceMax(float v) {
#pragma unroll
  for (int o = 32; o > 0; o >>= 1) v = fmaxf(v, __shfl_xor(v, o));
  return v;
}
__device__ float blockReduceSum256(float v) {
  __shared__ float sm[4];
  int lane = threadIdx.x & 63, w = threadIdx.x >> 6;
  v = waveReduceSum(v);
  if (lane == 0) sm[w] = v;
  __syncthreads();
  float r = sm[0] + sm[1] + sm[2] + sm[3];
  __syncthreads();
  return r;
}
__device__ float blockReduceMax256(float v) {
  __shared__ float sm[4];
  int lane = threadIdx.x & 63, w = threadIdx.x >> 6;
  v = waveReduceMax(v);
  if (lane == 0) sm[w] = v;
  __syncthreads();
  float r = fmaxf(fmaxf(sm[0], sm[1]), fmaxf(sm[2], sm[3]));
  __syncthreads();
  return r;
}
__device__ float blockReduceSum512(float v) {
  __shared__ float sm[8];
  int lane = threadIdx.x & 63, w = threadIdx.x >> 6;
  v = waveReduceSum(v);
  if (lane == 0) sm[w] = v;
  __syncthreads();
  float r = 0.f;
#pragma unroll
  for (int i = 0; i < 8; ++i) r += sm[i];
  __syncthreads();
  return r;
}
__device__ float blockReduceMax512(float v) {
  __shared__ float sm[8];
  int lane = threadIdx.x & 63, w = threadIdx.x >> 6;
  v = waveReduceMax(v);
  if (lane == 0) sm[w] = v;
  __syncthreads();
  float r = -3.4e38f;
#pragma unroll
  for (int i = 0; i < 8; ++i) r = fmaxf(r, sm[i]);
  __syncthreads();
  return r;
}

// ---------------- bf16 MFMA GEMM (dual operand-set) ----------------
// For by < M1b: set1; else set2 with row0 rebased. C = A @ Bt^T (+bias).
// ZC0: zero output col 0 (fused proj_tan0).
template <int BIAS, int OUTF32, int OUTBF16, int ZC0>
__global__ __launch_bounds__(256) void mfma_gemm2(
    const ushort_t* __restrict__ A1, const ushort_t* __restrict__ Bt1,
    const float* __restrict__ bias1, float* __restrict__ C1,
    ushort_t* __restrict__ Cb1, int M1b,
    const ushort_t* __restrict__ A2, const ushort_t* __restrict__ Bt2,
    const float* __restrict__ bias2, float* __restrict__ C2,
    ushort_t* __restrict__ Cb2, int N, int K) {
  __shared__ __align__(16) ushort_t Abuf[128 * 32];
  __shared__ __align__(16) ushort_t Bbuf[128 * 32];
  const int by = blockIdx.y;
  const bool sel = (by >= M1b);
  const ushort_t* A = sel ? A2 : A1;
  const ushort_t* Bt = sel ? Bt2 : Bt1;
  const float* bias = sel ? bias2 : bias1;
  float* C = sel ? C2 : C1;
  ushort_t* Cb = sel ? Cb2 : Cb1;
  const int row0 = (sel ? (by - M1b) : by) * 128;
  const int col0 = blockIdx.x * 128;

  const int tid = threadIdx.x;
  const int lane = tid & 63, w = tid >> 6;
  const int wr = w >> 1, wc = w & 1;
  const int s_r = lane & 15, s_kq = lane >> 4;

  const size_t a_src0 = (size_t)(row0 + (w * 2 + 0) * 16 + s_r) * K + s_kq * 8;
  const size_t a_src1 = (size_t)(row0 + (w * 2 + 1) * 16 + s_r) * K + s_kq * 8;
  const size_t b_src0 = (size_t)(col0 + (w * 2 + 0) * 16 + s_r) * K + s_kq * 8;
  const size_t b_src1 = (size_t)(col0 + (w * 2 + 1) * 16 + s_r) * K + s_kq * 8;
  ushort_t* a_dst0 = Abuf + (w * 2 + 0) * 512;
  ushort_t* a_dst1 = Abuf + (w * 2 + 1) * 512;
  ushort_t* b_dst0 = Bbuf + (w * 2 + 0) * 512;
  ushort_t* b_dst1 = Bbuf + (w * 2 + 1) * 512;

  f32x4 acc[4][4];
#pragma unroll
  for (int i = 0; i < 4; ++i)
#pragma unroll
    for (int j = 0; j < 4; ++j) acc[i][j] = (f32x4){0.f, 0.f, 0.f, 0.f};

  for (int k0 = 0; k0 < K; k0 += 32) {
    gld_lds16(A + a_src0 + k0, a_dst0);
    gld_lds16(A + a_src1 + k0, a_dst1);
    gld_lds16(Bt + b_src0 + k0, b_dst0);
    gld_lds16(Bt + b_src1 + k0, b_dst1);
    __syncthreads();
    bf16x8 af[4], bfr[4];
#pragma unroll
    for (int mi = 0; mi < 4; ++mi)
      af[mi] = *(const bf16x8*)(Abuf + (wr * 4 + mi) * 512 + lane * 8);
#pragma unroll
    for (int nj = 0; nj < 4; ++nj)
      bfr[nj] = *(const bf16x8*)(Bbuf + (wc * 4 + nj) * 512 + lane * 8);
#pragma unroll
    for (int mi = 0; mi < 4; ++mi)
#pragma unroll
      for (int nj = 0; nj < 4; ++nj)
        acc[mi][nj] = __builtin_amdgcn_mfma_f32_16x16x32_bf16(
            af[mi], bfr[nj], acc[mi][nj], 0, 0, 0);
    __syncthreads();
  }

#pragma unroll
  for (int nj = 0; nj < 4; ++nj) {
    const int n = col0 + wc * 64 + nj * 16 + (lane & 15);
    const float bb = BIAS ? bias[n] : 0.f;
#pragma unroll
    for (int mi = 0; mi < 4; ++mi) {
      f32x4 v = acc[mi][nj];
#pragma unroll
      for (int r = 0; r < 4; ++r) {
        const int m = row0 + wr * 64 + mi * 16 + (lane >> 4) * 4 + r;
        float val = v[r] + bb;
        if (ZC0 && n == 0) val = 0.f;
        if (OUTF32) C[(size_t)m * N + n] = val;
        if (OUTBF16) Cb[(size_t)m * N + n] = f2bf(val);
      }
    }
  }
}

// ---------------- pre-cast kernels ----------------
// merged gather: blocks [0,MQT) -> gq, [MQT, MQT+MKT) -> gk
__global__ __launch_bounds__(256) void gather_all_k(
    const int* __restrict__ qid, const int* __restrict__ kid,
    const float* __restrict__ emb, ushort_t* __restrict__ gq,
    ushort_t* __restrict__ gk) {
  int m = blockIdx.x;
  const int* ids;
  ushort_t* outp;
  if (m < MQT) {
    ids = qid + m * 3;
    outp = gq + (size_t)m * KP;
  } else {
    m -= MQT;
    ids = kid + m * 3;
    outp = gk + (size_t)m * KP;
  }
  const int t = threadIdx.x;
  if (t >= KP / 4) return;
  const int k = t * 4;
  ushort4 o = make_ushort4(0, 0, 0, 0);
  if (k < KIN) {
    const int node = (k >= 600) ? 2 : ((k >= 300) ? 1 : 0);
    const int off = k - node * 300;
    const int id = ids[node];
    float4 v = *(const float4*)(emb + (size_t)id * 300 + off);
    if (v.x != v.x) v.x = 0.f;
    if (v.y != v.y) v.y = 0.f;
    if (v.z != v.z) v.z = 0.f;
    if (v.w != v.w) v.w = 0.f;
    o = make_ushort4(f2bf(v.x), f2bf(v.y), f2bf(v.z), f2bf(v.w));
  }
  *(ushort4*)(outp + k) = o;
}

// merged transpose-cast: z=0 q2h, z=1 k2h, z=2..4 Wk[i], z=5..7 Wq[i]
// src [R][Cc] f32 -> dst [Cc][Rp] bf16 transposed (pad r>=R with 0)
__global__ __launch_bounds__(256) void tcast8_k(
    const float* __restrict__ q2h_w, const float* __restrict__ k2h_w,
    const float* __restrict__ Wk, const float* __restrict__ Wq,
    ushort_t* __restrict__ q2h_wt, ushort_t* __restrict__ k2h_wt,
    ushort_t* __restrict__ Wkt, ushort_t* __restrict__ Wqt) {
  const int z = blockIdx.z;
  const float* src;
  ushort_t* dst;
  int R, Rp;
  if (z == 0) { src = q2h_w; dst = q2h_wt; R = KIN; Rp = KP; }
  else if (z == 1) { src = k2h_w; dst = k2h_wt; R = KIN; Rp = KP; }
  else if (z < 5) {
    int i = z - 2;
    src = Wk + (size_t)i * HID * HID; dst = Wkt + (size_t)i * HID * HID;
    R = HID; Rp = HID;
  } else {
    int i = z - 5;
    src = Wq + (size_t)i * HID * HID; dst = Wqt + (size_t)i * HID * HID;
    R = HID; Rp = HID;
  }
  const int Cc = HID;
  if (blockIdx.y * 32 >= Rp) return;
  __shared__ float t[32][33];
  const int tx = threadIdx.x & 31, ty = threadIdx.x >> 5;
  const int r0 = blockIdx.y * 32, c0 = blockIdx.x * 32;
#pragma unroll
  for (int i = 0; i < 4; ++i) {
    int r = r0 + ty + i * 8, c = c0 + tx;
    t[ty + i * 8][tx] = (r < R) ? src[(size_t)r * Cc + c] : 0.f;
  }
  __syncthreads();
#pragma unroll
  for (int i = 0; i < 4; ++i) {
    int c = c0 + ty + i * 8, r = r0 + tx;
    if (r < Rp) dst[(size_t)c * Rp + r] = f2bf(t[tx][ty + i * 8]);
  }
}

// src [R][C] f32 -> dst [R][Cp] bf16 (pad cols with 0)
__global__ __launch_bounds__(128) void cast_pad_rows_k(
    const float* __restrict__ src, ushort_t* __restrict__ dst, int C, int Cp) {
  const int r = blockIdx.x, t = threadIdx.x;
  const int k = t * 4;
  if (k >= Cp) return;
  ushort4 o = make_ushort4(0, 0, 0, 0);
  if (k < C) {
    float4 v = *(const float4*)(src + (size_t)r * C + k);
    o = make_ushort4(f2bf(v.x), f2bf(v.y), f2bf(v.z), f2bf(v.w));
  }
  *(ushort4*)(dst + (size_t)r * Cp + k) = o;
}

// ---------------- small fp32 GEMM (head): C[M,N] = A[M,K]@B[K,N] ----------
// 16x64 tile per block, 256 threads, 4 outputs/thread (4 rows x 1 col).
template <int RELU, int OUTBF>
__global__ __launch_bounds__(256) void small_gemm(
    const float* __restrict__ A, const float* __restrict__ B,
    const float* __restrict__ bias, float* __restrict__ C,
    ushort_t* __restrict__ Cb, int M, int N, int K, int CP) {
  __shared__ float Ach[16][68];
  const int tid = threadIdx.x;
  const int tn = tid & 63, mg = tid >> 6;
  const int n = blockIdx.x * 64 + tn;
  const int row0 = blockIdx.y * 16;
  const int n_ld = (n < N) ? n : (N - 1);
  float acc[4] = {0.f, 0.f, 0.f, 0.f};
  for (int kc = 0; kc < K; kc += 64) {
    {
      const int r = tid >> 4, c4 = (tid & 15) * 4;
      float4 v = *(const float4*)(A + (size_t)(row0 + r) * K + kc + c4);
      Ach[r][c4] = v.x; Ach[r][c4 + 1] = v.y;
      Ach[r][c4 + 2] = v.z; Ach[r][c4 + 3] = v.w;
    }
    __syncthreads();
#pragma unroll 4
    for (int kk = 0; kk < 64; ++kk) {
      float bv = B[(size_t)(kc + kk) * N + n_ld];
#pragma unroll
      for (int r = 0; r < 4; ++r)
        acc[r] = fmaf(Ach[mg * 4 + r][kk], bv, acc[r]);
    }
    __syncthreads();
  }
  const float bb = (n < N) ? bias[n] : 0.f;
#pragma unroll
  for (int r = 0; r < 4; ++r) {
    float v = acc[r] + bb;
    if (RELU) v = fmaxf(v, 0.f);
    const int m = row0 + mg * 4 + r;
    if (OUTBF) {
      Cb[(size_t)m * CP + n] = (n < N) ? f2bf(v) : (ushort_t)0;
    } else {
      if (n < N) C[(size_t)m * N + n] = v;
    }
  }
}

// ---------------- fused attention (one block per batch) ----------------
// phase1: S = SCALE*kp@qp^T via MFMA -> LDS; wave3 stages qt_old bf16 -> LDS
// phase2a: Pq = softmax over kr (cols) -> Pq_lds ; 2b: Pk = softmax rows, in-place
// phase3: att_q = Pq@kt + qt_old -> Xq_new f32 + qtb_new bf16
// phase4: att_k = Pk@qt_old + kt -> Xk/Xkb IN PLACE (same-column discipline)
__global__ __launch_bounds__(256) void att_fused_k(
    const ushort_t* __restrict__ kp, const ushort_t* __restrict__ qp,
    const ushort_t* __restrict__ qtb_old, const float* __restrict__ Xq_old,
    float* __restrict__ Xq_new, ushort_t* __restrict__ qtb_new,
    float* __restrict__ Xk, ushort_t* __restrict__ Xkb) {
  const int b = blockIdx.x;
  __shared__ float S_lds[NK][33];        // scores -> Pk in place (13.2 KB)
  __shared__ float Pq[NQ][NK + 4];       // 12.5 KB
  __shared__ __align__(16) ushort_t qts[NQ * HID];  // 30 KB
  const int tid = threadIdx.x;
  const int w = tid >> 6, lane = tid & 63;

  // ---- phase 1 ----
  {
    const int r = lane & 15, kq = lane >> 4;
    const ushort_t* kpb = kp + (size_t)b * NK * HID;
    const ushort_t* qpb = qp + (size_t)b * NQ * HID;
    if (w == 3) {
      const uint4* src = (const uint4*)(qtb_old + (size_t)b * NQ * HID);
      uint4* dst = (uint4*)qts;
#pragma unroll
      for (int it = 0; it < 30; ++it) dst[it * 64 + lane] = src[it * 64 + lane];
    }
    const int rowA = w * 16 + r;
    const int rowB = 64 + w * 16 + r;
    const int rowB_c = rowB < NK ? rowB : NK - 1;
    const int qr1 = (16 + r) < NQ ? (16 + r) : NQ - 1;
    const bool hasB = (w < 3);
    f32x4 aA0 = {0.f, 0.f, 0.f, 0.f}, aA1 = {0.f, 0.f, 0.f, 0.f};
    f32x4 aB0 = {0.f, 0.f, 0.f, 0.f}, aB1 = {0.f, 0.f, 0.f, 0.f};
    for (int k0 = 0; k0 < HID; k0 += 32) {
      bf16x8 b0 = *(const bf16x8*)(qpb + (size_t)r * HID + k0 + kq * 8);
      bf16x8 b1 = *(const bf16x8*)(qpb + (size_t)qr1 * HID + k0 + kq * 8);
      bf16x8 afA = *(const bf16x8*)(kpb + (size_t)rowA * HID + k0 + kq * 8);
      aA0 = __builtin_amdgcn_mfma_f32_16x16x32_bf16(afA, b0, aA0, 0, 0, 0);
      aA1 = __builtin_amdgcn_mfma_f32_16x16x32_bf16(afA, b1, aA1, 0, 0, 0);
      if (hasB) {
        bf16x8 afB = *(const bf16x8*)(kpb + (size_t)rowB_c * HID + k0 + kq * 8);
        aB0 = __builtin_amdgcn_mfma_f32_16x16x32_bf16(afB, b0, aB0, 0, 0, 0);
        aB1 = __builtin_amdgcn_mfma_f32_16x16x32_bf16(afB, b1, aB1, 0, 0, 0);
      }
    }
    const int q0 = lane & 15, mb = (lane >> 4) * 4;
#pragma unroll
    for (int rr = 0; rr < 4; ++rr) {
      const int mA = w * 16 + mb + rr;
      S_lds[mA][q0] = aA0[rr] * SCALE;
      if (q0 + 16 < NQ) S_lds[mA][q0 + 16] = aA1[rr] * SCALE;
      if (hasB) {
        const int mB = 64 + w * 16 + mb + rr;
        if (mB < NK) {
          S_lds[mB][q0] = aB0[rr] * SCALE;
          if (q0 + 16 < NQ) S_lds[mB][q0 + 16] = aB1[rr] * SCALE;
        }
      }
    }
  }
  __syncthreads();
  // ---- phase 2a: Pq ----
  if (tid < NQ) {
    const int q = tid;
    float m = -1e30f;
    for (int kr = 0; kr < NK; ++kr) m = fmaxf(m, S_lds[kr][q]);
    float s = 0.f;
    for (int kr = 0; kr < NK; ++kr) {
      float e = expf(S_lds[kr][q] - m);
      Pq[q][kr] = e;
      s += e;
    }
    float inv = 1.f / s;
    for (int kr = 0; kr < NK; ++kr) Pq[q][kr] *= inv;
  }
  __syncthreads();
  // ---- phase 2b: Pk in place ----
  if (tid < NK) {
    const int kr = tid;
    float m = -1e30f;
#pragma unroll
    for (int q = 0; q < NQ; ++q) m = fmaxf(m, S_lds[kr][q]);
    float s = 0.f;
    float e[NQ];
#pragma unroll
    for (int q = 0; q < NQ; ++q) {
      e[q] = expf(S_lds[kr][q] - m);
      s += e[q];
    }
    float inv = 1.f / s;
#pragma unroll
    for (int q = 0; q < NQ; ++q) S_lds[kr][q] = e[q] * inv;
  }
  __syncthreads();
  const int c2 = tid;  // float2 column index
  const float* ktp = Xk + (size_t)b * NK * HID;
  // ---- phase 3: att_q ----
  {
    float ax[NQ], ay[NQ];
#pragma unroll
    for (int q = 0; q < NQ; ++q) { ax[q] = 0.f; ay[q] = 0.f; }
    for (int kr = 0; kr < NK; ++kr) {
      float2 kv = *(const float2*)(ktp + (size_t)kr * HID + c2 * 2);
#pragma unroll
      for (int q = 0; q < NQ; ++q) {
        float p = Pq[q][kr];
        ax[q] = fmaf(p, kv.x, ax[q]);
        ay[q] = fmaf(p, kv.y, ay[q]);
      }
    }
#pragma unroll
    for (int q = 0; q < NQ; ++q) {
      const size_t off = ((size_t)b * NQ + q) * HID + c2 * 2;
      float2 res = *(const float2*)(Xq_old + off);
      float ox = ax[q] + res.x, oy = ay[q] + res.y;
      *(float2*)(Xq_new + off) = make_float2(ox, oy);
      *(ushort2*)(qtb_new + off) = make_ushort2(f2bf(ox), f2bf(oy));
    }
  }
  // ---- phase 4: att_k (no sync: each thread owns its columns of Xk) ----
  {
    float qx[NQ], qy[NQ];
#pragma unroll
    for (int q = 0; q < NQ; ++q) {
      unsigned int u = *(const unsigned int*)(qts + q * HID + c2 * 2);
      qx[q] = bf2f((unsigned short)(u & 0xFFFFu));
      qy[q] = bf2f((unsigned short)(u >> 16));
    }
    float* xk = Xk + (size_t)b * NK * HID;
    ushort_t* xkb = Xkb + (size_t)b * NK * HID;
    for (int kr = 0; kr < NK; ++kr) {
      const size_t off = (size_t)kr * HID + c2 * 2;
      float2 a = *(const float2*)(xk + off);
#pragma unroll
      for (int q = 0; q < NQ; ++q) {
        float p = S_lds[kr][q];
        a.x = fmaf(p, qx[q], a.x);
        a.y = fmaf(p, qy[q], a.y);
      }
      *(float2*)(xk + off) = a;
      *(ushort2*)(xkb + off) = make_ushort2(f2bf(a.x), f2bf(a.y));
    }
  }
}

// ---------------- hyperbolic boundary ops ----------------
// merged: rows [0,MKT) -> Xk, rows [MKT, MKT+MQT) -> Xq ; in-place expproj
__global__ __launch_bounds__(256) void expproj_all_k(
    float* __restrict__ Xk, float* __restrict__ Xq,
    const float* __restrict__ curv, int ci) {
  const int row = blockIdx.x, tid = threadIdx.x;
  float* x = (row < MKT) ? (Xk + (size_t)row * HID)
                         : (Xq + (size_t)(row - MKT) * HID);
  const float c = curv[ci];
  const float Kc = 1.f / c, sqrtK = sqrtf(Kc);
  float ss = 0.f;
  for (int d = 1 + tid; d < HID; d += 256) {
    float v = x[d];
    ss += v * v;
  }
  ss = blockReduceSum256(ss);
  float n = fmaxf(sqrtf(ss), 1e-15f);
  float theta = n / sqrtK;
  float f = sqrtK * sinhf(theta) / n;
  float ss2 = f * f * ss;
  float first = sqrtf(fmaxf(Kc + ss2, 1e-7f));
  for (int d = 1 + tid; d < HID; d += 256) x[d] = f * x[d];
  if (tid == 0) x[0] = first;
}

// in-place proj_tan0(logmap0(x, c))
__global__ __launch_bounds__(256) void logmap_kernel(
    float* __restrict__ x_, int D, const float* __restrict__ curv, int ci) {
  const int row = blockIdx.x, tid = threadIdx.x;
  float* x = x_ + (size_t)row * D;
  const float c = curv[ci];
  const float Kc = 1.f / c, sqrtK = sqrtf(Kc);
  float x0 = x[0];
  float ss = 0.f;
  for (int d = 1 + tid; d < D; d += 256) {
    float v = x[d];
    ss += v * v;
  }
  ss = blockReduceSum256(ss);
  float n = fmaxf(sqrtf(ss), 1e-15f);
  float theta = fmaxf(x0 / sqrtK, 1.f + 1e-7f);
  float r = sqrtK * acoshf(theta) / n;
  for (int d = 1 + tid; d < D; d += 256) x[d] = r * x[d];
  if (tid == 0) x[0] = 0.f;
}

// ---------------- tail ----------------
__global__ __launch_bounds__(512) void mean_kernel(
    const float* __restrict__ kx, const float* __restrict__ qx,
    float* __restrict__ last) {
  const int b = blockIdx.x, tid = threadIdx.x;
  float sk = 0.f;
  for (int r = 0; r < NK; ++r) sk += kx[((size_t)b * NK + r) * HID + tid];
  float sq = 0.f;
  for (int r = 0; r < NQ; ++r) sq += qx[((size_t)b * NQ + r) * HID + tid];
  last[(size_t)b * 1024 + tid] = sk * (1.f / NK);
  last[(size_t)b * 1024 + HID + tid] = sq * (1.f / NQ);
}

__global__ __launch_bounds__(512) void logsoftmax_k(float* __restrict__ x) {
  const int b = blockIdx.x, tid = threadIdx.x;
  float4* row = (float4*)(x + (size_t)b * NANS);
  float m = -3.4e38f;
  for (int i = tid; i < NANS / 4; i += 512) {
    float4 v = row[i];
    m = fmaxf(fmaxf(fmaxf(m, v.x), v.y), fmaxf(v.z, v.w));
  }
  m = blockReduceMax512(m);
  float s = 0.f;
  for (int i = tid; i < NANS / 4; i += 512) {
    float4 v = row[i];
    s += expf(v.x - m) + expf(v.y - m) + expf(v.z - m) + expf(v.w - m);
  }
  s = blockReduceSum512(s);
  float lse = m + logf(s);
  for (int i = tid; i < NANS / 4; i += 512) {
    float4 v = row[i];
    v.x -= lse; v.y -= lse; v.z -= lse; v.w -= lse;
    row[i] = v;
  }
}

// ---------------- launch ----------------
extern "C" void kernel_launch(void* const* d_in, const int* in_sizes, int n_in,
                              void* d_out, int out_size, void* d_ws, size_t ws_size,
                              hipStream_t stream) {
  const int* qid = (const int*)d_in[0];
  const int* kid = (const int*)d_in[1];
  const float* emb = (const float*)d_in[2];
  const float* q2h_w = (const float*)d_in[3];
  const float* q2h_b = (const float*)d_in[4];
  const float* k2h_w = (const float*)d_in[5];
  const float* k2h_b = (const float*)d_in[6];
  const float* Wk = (const float*)d_in[7];
  const float* Wq = (const float*)d_in[8];
  const float* curv = (const float*)d_in[9];
  const float* p1w = (const float*)d_in[10];
  const float* p1b = (const float*)d_in[11];
  const float* p2w = (const float*)d_in[12];
  const float* p2b = (const float*)d_in[13];
  const float* glove = (const float*)d_in[14];
  float* out = (float*)d_out;

  // ---- workspace layout ----
  float* f = (float*)d_ws;
  float* Xk = f;                               // 25600*512 (kt, in-place)
  float* Xq0 = Xk + (size_t)MKT * HID;         // 7680*512 (qt ping)
  float* Xq1 = Xq0 + (size_t)MQT * HID;        // 7680*512 (qt pong)
  float* last = Xq1 + (size_t)MQT * HID;       // 256*1024
  float* h1 = last + (size_t)BATCH * 1024;     // 256*512
  float* fend = h1 + (size_t)BATCH * HID;

  ushort_t* u = (ushort_t*)fend;
  ushort_t* gk = u;                            // 25600*928 (later gloveb)
  ushort_t* gq = gk + (size_t)MKT * KP;        // 7680*928
  ushort_t* Xkb = gq + (size_t)MQT * KP;       // 25600*512 (kt bf16, in-place)
  ushort_t* kpb = Xkb + (size_t)MKT * HID;     // 25600*512 (kp scratch)
  ushort_t* qb0 = kpb + (size_t)MKT * HID;     // 7680*512 (qt bf16 ping)
  ushort_t* qb1 = qb0 + (size_t)MQT * HID;     // 7680*512 (qp / qt bf16 pong)
  ushort_t* q2h_wt = qb1 + (size_t)MQT * HID;  // 512*928
  ushort_t* k2h_wt = q2h_wt + (size_t)HID * KP;
  ushort_t* Wkt = k2h_wt + (size_t)HID * KP;   // 3*512*512
  ushort_t* Wqt = Wkt + (size_t)NLAYERS * HID * HID;
  ushort_t* o2b = Wqt + (size_t)NLAYERS * HID * HID;  // 256*320
  ushort_t* gloveb = gk;  // overlay (gk dead after input GEMM)

  // ---- pre-casts (merged) ----
  gather_all_k<<<MQT + MKT, 256, 0, stream>>>(qid, kid, emb, gq, gk);
  tcast8_k<<<dim3(HID / 32, KP / 32, 8), 256, 0, stream>>>(
      q2h_w, k2h_w, Wk, Wq, q2h_wt, k2h_wt, Wkt, Wqt);

  // ---- input projections (merged q+k), fused proj_tan0 ----
  mfma_gemm2<1, 1, 1, 1><<<dim3(HID / 128, MQT / 128 + MKT / 128), 256, 0, stream>>>(
      gq, q2h_wt, q2h_b, Xq0, qb0, MQT / 128,
      gk, k2h_wt, k2h_b, Xk, Xkb, HID, KP);

  // glove cast (overlays gk, now dead)
  cast_pad_rows_k<<<NANS, 128, 0, stream>>>(glove, gloveb, NOUT, NOUTP);

  // ---- layers in tangent space ----
  float* Xq_cur = Xq0;
  float* Xq_alt = Xq1;
  ushort_t* Xqb_cur = qb0;
  ushort_t* Xqb_alt = qb1;
  for (int i = 0; i < NLAYERS; ++i) {
    mfma_gemm2<0, 0, 1, 0><<<dim3(HID / 128, MKT / 128 + MQT / 128), 256, 0, stream>>>(
        Xkb, Wkt + (size_t)i * HID * HID, nullptr, nullptr, kpb, MKT / 128,
        Xqb_cur, Wqt + (size_t)i * HID * HID, nullptr, nullptr, Xqb_alt, HID, HID);
    att_fused_k<<<BATCH, 256, 0, stream>>>(
        kpb, Xqb_alt, Xqb_cur, Xq_cur, Xq_alt, Xqb_alt, Xk, Xkb);
    float* tf = Xq_cur; Xq_cur = Xq_alt; Xq_alt = tf;
    ushort_t* tu = Xqb_cur; Xqb_cur = Xqb_alt; Xqb_alt = tu;
  }

  // ---- boundary: to hyperbolic, mean, back to tangent ----
  expproj_all_k<<<MKT + MQT, 256, 0, stream>>>(Xk, Xq_cur, curv, NLAYERS);
  mean_kernel<<<BATCH, 512, 0, stream>>>(Xk, Xq_cur, last);
  logmap_kernel<<<BATCH, 256, 0, stream>>>(last, 1024, curv, NLAYERS);

  // ---- head ----
  small_gemm<1, 0><<<dim3(HID / 64, BATCH / 16), 256, 0, stream>>>(
      last, p1w, p1b, h1, nullptr, BATCH, HID, 1024, HID);
  small_gemm<0, 1><<<dim3(NOUTP / 64, BATCH / 16), 256, 0, stream>>>(
      h1, p2w, p2b, nullptr, o2b, BATCH, NOUT, HID, NOUTP);
  mfma_gemm2<0, 1, 0, 0><<<dim3(NANS / 128, BATCH / 128), 256, 0, stream>>>(
      o2b, gloveb, nullptr, out, nullptr, BATCH / 128,
      o2b, gloveb, nullptr, out, nullptr, NANS, NOUTP);
  logsoftmax_k<<<BATCH, 512, 0, stream>>>(out);
}

// Round 6
// 705.719 us; speedup vs baseline: 6.1919x; 1.1568x over previous
//
#include <hip/hip_runtime.h>
#include <math.h>

// Problem constants (from setup_inputs)
#define BATCH 256
#define NQ 30
#define NK 100
#define HID 512
#define WORD 300
#define KIN 900          // WORD*3
#define KP 928           // KIN padded to multiple of 32
#define NANS 32000
#define NOUT 300
#define NOUTP 384        // NOUT padded to multiple of 128 (MFMA N-tile)
#define NLAYERS 3
#define MQT (BATCH * NQ)   // 7680
#define MKT (BATCH * NK)   // 25600
#define SCALE 0.044194173824159216f  // 1/sqrt(512)

typedef __attribute__((ext_vector_type(8))) short bf16x8;
typedef __attribute__((ext_vector_type(4))) float f32x4;
typedef unsigned short ushort_t;

__device__ __forceinline__ unsigned short f2bf(float f) {
  unsigned int u = __float_as_uint(f);
  u = (u + 0x7FFF + ((u >> 16) & 1)) >> 16;  // RNE
  return (unsigned short)u;
}
__device__ __forceinline__ float bf2f(unsigned short s) {
  return __uint_as_float(((unsigned int)s) << 16);
}

typedef const __attribute__((address_space(1))) unsigned int* gas_u32;
typedef __attribute__((address_space(3))) unsigned int* las_u32;
__device__ __forceinline__ void gld_lds16(const void* g, void* l) {
  __builtin_amdgcn_global_load_lds((gas_u32)g, (las_u32)l, 16, 0, 0);
}

// bijective XCD swizzle (m204): contiguous logical chunks per XCD
__device__ __forceinline__ int xcd_swz_linear() {
  const int nwg = gridDim.x * gridDim.y;
  const int orig = blockIdx.y * gridDim.x + blockIdx.x;
  const int q = nwg >> 3, r = nwg & 7;
  const int xcd = orig & 7, idx = orig >> 3;
  return (xcd < r ? xcd * (q + 1) : r * (q + 1) + (xcd - r) * q) + idx;
}

// ---------------- reduction helpers ----------------
__device__ __forceinline__ float waveReduceSum(float v) {
#pragma unroll
  for (int o = 32; o > 0; o >>= 1) v += __shfl_xor(v, o);
  return v;
}
__device__ __forceinline__ float waveReduceMax(float v) {
#pragma unroll
  for (int o = 32; o > 0; o >>= 1) v = fmaxf(v, __shfl_xor(v, o));
  return v;
}
__device__ float blockReduceSum256(float v) {
  __shared__ float sm[4];
  int lane = threadIdx.x & 63, w = threadIdx.x >> 6;
  v = waveReduceSum(v);
  if (lane == 0) sm[w] = v;
  __syncthreads();
  float r = sm[0] + sm[1] + sm[2] + sm[3];
  __syncthreads();
  return r;
}
__device__ float blockReduceSum512(float v) {
  __shared__ float sm[8];
  int lane = threadIdx.x & 63, w = threadIdx.x >> 6;
  v = waveReduceSum(v);
  if (lane == 0) sm[w] = v;
  __syncthreads();
  float r = 0.f;
#pragma unroll
  for (int i = 0; i < 8; ++i) r += sm[i];
  __syncthreads();
  return r;
}
__device__ float blockReduceMax512(float v) {
  __shared__ float sm[8];
  int lane = threadIdx.x & 63, w = threadIdx.x >> 6;
  v = waveReduceMax(v);
  if (lane == 0) sm[w] = v;
  __syncthreads();
  float r = -3.4e38f;
#pragma unroll
  for (int i = 0; i < 8; ++i) r = fmaxf(r, sm[i]);
  __syncthreads();
  return r;
}

// ---------------- bf16 MFMA GEMM (dual operand-set, XCD-swizzled) ----------
// For by < M1b: set1; else set2 rebased. C = A @ Bt^T (+bias[clamped at nbias]).
// ZC0: zero col 0 (fused proj_tan0). RELU: epilogue relu.
template <int BIAS, int OUTF32, int OUTBF16, int ZC0, int RELU>
__global__ __launch_bounds__(256) void mfma_gemm2(
    const ushort_t* __restrict__ A1, const ushort_t* __restrict__ Bt1,
    const float* __restrict__ bias1, float* __restrict__ C1,
    ushort_t* __restrict__ Cb1, int M1b,
    const ushort_t* __restrict__ A2, const ushort_t* __restrict__ Bt2,
    const float* __restrict__ bias2, float* __restrict__ C2,
    ushort_t* __restrict__ Cb2, int N, int K, int nbias) {
  __shared__ __align__(16) ushort_t Abuf[128 * 32];
  __shared__ __align__(16) ushort_t Bbuf[128 * 32];
  const int wg = xcd_swz_linear();
  const int bx = wg % gridDim.x, by = wg / gridDim.x;
  const bool sel = (by >= M1b);
  const ushort_t* A = sel ? A2 : A1;
  const ushort_t* Bt = sel ? Bt2 : Bt1;
  const float* bias = sel ? bias2 : bias1;
  float* C = sel ? C2 : C1;
  ushort_t* Cb = sel ? Cb2 : Cb1;
  const int row0 = (sel ? (by - M1b) : by) * 128;
  const int col0 = bx * 128;

  const int tid = threadIdx.x;
  const int lane = tid & 63, w = tid >> 6;
  const int wr = w >> 1, wc = w & 1;
  const int s_r = lane & 15, s_kq = lane >> 4;

  const size_t a_src0 = (size_t)(row0 + (w * 2 + 0) * 16 + s_r) * K + s_kq * 8;
  const size_t a_src1 = (size_t)(row0 + (w * 2 + 1) * 16 + s_r) * K + s_kq * 8;
  const size_t b_src0 = (size_t)(col0 + (w * 2 + 0) * 16 + s_r) * K + s_kq * 8;
  const size_t b_src1 = (size_t)(col0 + (w * 2 + 1) * 16 + s_r) * K + s_kq * 8;
  ushort_t* a_dst0 = Abuf + (w * 2 + 0) * 512;
  ushort_t* a_dst1 = Abuf + (w * 2 + 1) * 512;
  ushort_t* b_dst0 = Bbuf + (w * 2 + 0) * 512;
  ushort_t* b_dst1 = Bbuf + (w * 2 + 1) * 512;

  f32x4 acc[4][4];
#pragma unroll
  for (int i = 0; i < 4; ++i)
#pragma unroll
    for (int j = 0; j < 4; ++j) acc[i][j] = (f32x4){0.f, 0.f, 0.f, 0.f};

  for (int k0 = 0; k0 < K; k0 += 32) {
    gld_lds16(A + a_src0 + k0, a_dst0);
    gld_lds16(A + a_src1 + k0, a_dst1);
    gld_lds16(Bt + b_src0 + k0, b_dst0);
    gld_lds16(Bt + b_src1 + k0, b_dst1);
    __syncthreads();
    bf16x8 af[4], bfr[4];
#pragma unroll
    for (int mi = 0; mi < 4; ++mi)
      af[mi] = *(const bf16x8*)(Abuf + (wr * 4 + mi) * 512 + lane * 8);
#pragma unroll
    for (int nj = 0; nj < 4; ++nj)
      bfr[nj] = *(const bf16x8*)(Bbuf + (wc * 4 + nj) * 512 + lane * 8);
#pragma unroll
    for (int mi = 0; mi < 4; ++mi)
#pragma unroll
      for (int nj = 0; nj < 4; ++nj)
        acc[mi][nj] = __builtin_amdgcn_mfma_f32_16x16x32_bf16(
            af[mi], bfr[nj], acc[mi][nj], 0, 0, 0);
    __syncthreads();
  }

#pragma unroll
  for (int nj = 0; nj < 4; ++nj) {
    const int n = col0 + wc * 64 + nj * 16 + (lane & 15);
    const float bb = BIAS ? ((n < nbias) ? bias[n] : 0.f) : 0.f;
#pragma unroll
    for (int mi = 0; mi < 4; ++mi) {
      f32x4 v = acc[mi][nj];
#pragma unroll
      for (int r = 0; r < 4; ++r) {
        const int m = row0 + wr * 64 + mi * 16 + (lane >> 4) * 4 + r;
        float val = v[r] + bb;
        if (RELU) val = fmaxf(val, 0.f);
        if (ZC0 && n == 0) val = 0.f;
        if (OUTF32) C[(size_t)m * N + n] = val;
        if (OUTBF16) Cb[(size_t)m * N + n] = f2bf(val);
      }
    }
  }
}

// ---------------- pre-cast kernels ----------------
// merged gather: blocks [0,MQT) -> gq, [MQT, MQT+MKT) -> gk
__global__ __launch_bounds__(256) void gather_all_k(
    const int* __restrict__ qid, const int* __restrict__ kid,
    const float* __restrict__ emb, ushort_t* __restrict__ gq,
    ushort_t* __restrict__ gk) {
  int m = blockIdx.x;
  const int* ids;
  ushort_t* outp;
  if (m < MQT) {
    ids = qid + m * 3;
    outp = gq + (size_t)m * KP;
  } else {
    m -= MQT;
    ids = kid + m * 3;
    outp = gk + (size_t)m * KP;
  }
  const int t = threadIdx.x;
  if (t >= KP / 4) return;
  const int k = t * 4;
  ushort4 o = make_ushort4(0, 0, 0, 0);
  if (k < KIN) {
    const int node = (k >= 600) ? 2 : ((k >= 300) ? 1 : 0);
    const int off = k - node * 300;
    const int id = ids[node];
    float4 v = *(const float4*)(emb + (size_t)id * 300 + off);
    if (v.x != v.x) v.x = 0.f;
    if (v.y != v.y) v.y = 0.f;
    if (v.z != v.z) v.z = 0.f;
    if (v.w != v.w) v.w = 0.f;
    o = make_ushort4(f2bf(v.x), f2bf(v.y), f2bf(v.z), f2bf(v.w));
  }
  *(ushort4*)(outp + k) = o;
}

// merged transpose-cast, 10 jobs:
// z=0 q2h, z=1 k2h, z=2..4 Wk[i], z=5..7 Wq[i], z=8 p1w, z=9 p2w
// src [R][Cc] f32 -> dst [Cp][Rp] bf16: dst[c][r] = (r<R && c<Cc) ? src[r][c] : 0
__global__ __launch_bounds__(256) void tcast10_k(
    const float* __restrict__ q2h_w, const float* __restrict__ k2h_w,
    const float* __restrict__ Wk, const float* __restrict__ Wq,
    const float* __restrict__ p1w, const float* __restrict__ p2w,
    ushort_t* __restrict__ q2h_wt, ushort_t* __restrict__ k2h_wt,
    ushort_t* __restrict__ Wkt, ushort_t* __restrict__ Wqt,
    ushort_t* __restrict__ p1wt, ushort_t* __restrict__ p2wt) {
  const int z = blockIdx.z;
  const float* src;
  ushort_t* dst;
  int R, Cc, Rp, Cp;
  if (z == 0)      { src = q2h_w; dst = q2h_wt; R = KIN;  Cc = HID;  Rp = KP;   Cp = HID; }
  else if (z == 1) { src = k2h_w; dst = k2h_wt; R = KIN;  Cc = HID;  Rp = KP;   Cp = HID; }
  else if (z < 5)  { int i = z - 2; src = Wk + (size_t)i * HID * HID; dst = Wkt + (size_t)i * HID * HID; R = HID; Cc = HID; Rp = HID; Cp = HID; }
  else if (z < 8)  { int i = z - 5; src = Wq + (size_t)i * HID * HID; dst = Wqt + (size_t)i * HID * HID; R = HID; Cc = HID; Rp = HID; Cp = HID; }
  else if (z == 8) { src = p1w; dst = p1wt; R = 1024; Cc = HID;  Rp = 1024; Cp = HID; }
  else             { src = p2w; dst = p2wt; R = HID;  Cc = NOUT; Rp = HID;  Cp = NOUTP; }
  const int r0 = blockIdx.y * 32, c0 = blockIdx.x * 32;
  if (r0 >= Rp || c0 >= Cp) return;
  __shared__ float t[32][33];
  const int tx = threadIdx.x & 31, ty = threadIdx.x >> 5;
#pragma unroll
  for (int i = 0; i < 4; ++i) {
    int r = r0 + ty + i * 8, c = c0 + tx;
    t[ty + i * 8][tx] = (r < R && c < Cc) ? src[(size_t)r * Cc + c] : 0.f;
  }
  __syncthreads();
#pragma unroll
  for (int i = 0; i < 4; ++i) {
    int c = c0 + ty + i * 8, r = r0 + tx;
    if (c < Cp && r < Rp) dst[(size_t)c * Rp + r] = f2bf(t[tx][ty + i * 8]);
  }
}

// src [R][C] f32 -> dst [R][Cp] bf16 (pad cols with 0)
__global__ __launch_bounds__(128) void cast_pad_rows_k(
    const float* __restrict__ src, ushort_t* __restrict__ dst, int C, int Cp) {
  const int r = blockIdx.x, t = threadIdx.x;
  const int k = t * 4;
  if (k >= Cp) return;
  ushort4 o = make_ushort4(0, 0, 0, 0);
  if (k < C) {
    float4 v = *(const float4*)(src + (size_t)r * C + k);
    o = make_ushort4(f2bf(v.x), f2bf(v.y), f2bf(v.z), f2bf(v.w));
  }
  *(ushort4*)(dst + (size_t)r * Cp + k) = o;
}

// ---------------- fused attention (one block per batch) ----------------
// phase1: S = SCALE*kp@qp^T via MFMA -> LDS; wave3 stages qt_old bf16 -> LDS
// phase2a: Pq = softmax over kr (cols); 2b: Pk = softmax rows, in place
// phase3+4 fused: one pass over kr: read kt once; accumulate att_q AND write
//   att_k = kt + Pk@qt_old in place (same-column discipline, no extra sync)
__global__ __launch_bounds__(256) void att_fused_k(
    const ushort_t* __restrict__ kp, const ushort_t* __restrict__ qp,
    const ushort_t* __restrict__ qtb_old, const float* __restrict__ Xq_old,
    float* __restrict__ Xq_new, ushort_t* __restrict__ qtb_new,
    float* __restrict__ Xk, ushort_t* __restrict__ Xkb) {
  const int b = blockIdx.x;
  __shared__ float S_lds[NK][33];        // scores -> Pk in place
  __shared__ float Pq[NQ][NK + 4];
  __shared__ __align__(16) ushort_t qts[NQ * HID];  // 30 KB
  const int tid = threadIdx.x;
  const int w = tid >> 6, lane = tid & 63;

  // ---- phase 1 ----
  {
    const int r = lane & 15, kq = lane >> 4;
    const ushort_t* kpb = kp + (size_t)b * NK * HID;
    const ushort_t* qpb = qp + (size_t)b * NQ * HID;
    if (w == 3) {
      const uint4* src = (const uint4*)(qtb_old + (size_t)b * NQ * HID);
      uint4* dst = (uint4*)qts;
#pragma unroll
      for (int it = 0; it < 30; ++it) dst[it * 64 + lane] = src[it * 64 + lane];
    }
    const int rowA = w * 16 + r;
    const int rowB = 64 + w * 16 + r;
    const int rowB_c = rowB < NK ? rowB : NK - 1;
    const int qr1 = (16 + r) < NQ ? (16 + r) : NQ - 1;
    const bool hasB = (w < 3);
    f32x4 aA0 = {0.f, 0.f, 0.f, 0.f}, aA1 = {0.f, 0.f, 0.f, 0.f};
    f32x4 aB0 = {0.f, 0.f, 0.f, 0.f}, aB1 = {0.f, 0.f, 0.f, 0.f};
    for (int k0 = 0; k0 < HID; k0 += 32) {
      bf16x8 b0 = *(const bf16x8*)(qpb + (size_t)r * HID + k0 + kq * 8);
      bf16x8 b1 = *(const bf16x8*)(qpb + (size_t)qr1 * HID + k0 + kq * 8);
      bf16x8 afA = *(const bf16x8*)(kpb + (size_t)rowA * HID + k0 + kq * 8);
      aA0 = __builtin_amdgcn_mfma_f32_16x16x32_bf16(afA, b0, aA0, 0, 0, 0);
      aA1 = __builtin_amdgcn_mfma_f32_16x16x32_bf16(afA, b1, aA1, 0, 0, 0);
      if (hasB) {
        bf16x8 afB = *(const bf16x8*)(kpb + (size_t)rowB_c * HID + k0 + kq * 8);
        aB0 = __builtin_amdgcn_mfma_f32_16x16x32_bf16(afB, b0, aB0, 0, 0, 0);
        aB1 = __builtin_amdgcn_mfma_f32_16x16x32_bf16(afB, b1, aB1, 0, 0, 0);
      }
    }
    const int q0 = lane & 15, mb = (lane >> 4) * 4;
#pragma unroll
    for (int rr = 0; rr < 4; ++rr) {
      const int mA = w * 16 + mb + rr;
      S_lds[mA][q0] = aA0[rr] * SCALE;
      if (q0 + 16 < NQ) S_lds[mA][q0 + 16] = aA1[rr] * SCALE;
      if (hasB) {
        const int mB = 64 + w * 16 + mb + rr;
        if (mB < NK) {
          S_lds[mB][q0] = aB0[rr] * SCALE;
          if (q0 + 16 < NQ) S_lds[mB][q0 + 16] = aB1[rr] * SCALE;
        }
      }
    }
  }
  __syncthreads();
  // ---- phase 2a: Pq (softmax over kr per q) ----
  if (tid < NQ) {
    const int q = tid;
    float m = -1e30f;
    for (int kr = 0; kr < NK; ++kr) m = fmaxf(m, S_lds[kr][q]);
    float s = 0.f;
    for (int kr = 0; kr < NK; ++kr) {
      float e = expf(S_lds[kr][q] - m);
      Pq[q][kr] = e;
      s += e;
    }
    float inv = 1.f / s;
    for (int kr = 0; kr < NK; ++kr) Pq[q][kr] *= inv;
  }
  __syncthreads();
  // ---- phase 2b: Pk in place ----
  if (tid < NK) {
    const int kr = tid;
    float m = -1e30f;
#pragma unroll
    for (int q = 0; q < NQ; ++q) m = fmaxf(m, S_lds[kr][q]);
    float s = 0.f;
    float e[NQ];
#pragma unroll
    for (int q = 0; q < NQ; ++q) {
      e[q] = expf(S_lds[kr][q] - m);
      s += e[q];
    }
    float inv = 1.f / s;
#pragma unroll
    for (int q = 0; q < NQ; ++q) S_lds[kr][q] = e[q] * inv;
  }
  __syncthreads();
  // ---- fused phase 3+4 ----
  const int c2 = tid;  // float2 column index
  float qx[NQ], qy[NQ], ax[NQ], ay[NQ];
#pragma unroll
  for (int q = 0; q < NQ; ++q) {
    unsigned int u = *(const unsigned int*)(qts + q * HID + c2 * 2);
    qx[q] = bf2f((unsigned short)(u & 0xFFFFu));
    qy[q] = bf2f((unsigned short)(u >> 16));
    ax[q] = 0.f;
    ay[q] = 0.f;
  }
  float* xk = Xk + (size_t)b * NK * HID;
  ushort_t* xkb = Xkb + (size_t)b * NK * HID;
  for (int kr = 0; kr < NK; ++kr) {
    const size_t off = (size_t)kr * HID + c2 * 2;
    float2 kv = *(const float2*)(xk + off);
    float sx = kv.x, sy = kv.y;
#pragma unroll
    for (int q = 0; q < NQ; ++q) {
      float pq = Pq[q][kr];
      ax[q] = fmaf(pq, kv.x, ax[q]);
      ay[q] = fmaf(pq, kv.y, ay[q]);
      float pk = S_lds[kr][q];
      sx = fmaf(pk, qx[q], sx);
      sy = fmaf(pk, qy[q], sy);
    }
    *(float2*)(xk + off) = make_float2(sx, sy);
    *(ushort2*)(xkb + off) = make_ushort2(f2bf(sx), f2bf(sy));
  }
#pragma unroll
  for (int q = 0; q < NQ; ++q) {
    const size_t off = ((size_t)b * NQ + q) * HID + c2 * 2;
    float2 res = *(const float2*)(Xq_old + off);
    float ox = ax[q] + res.x, oy = ay[q] + res.y;
    *(float2*)(Xq_new + off) = make_float2(ox, oy);
    *(ushort2*)(qtb_new + off) = make_ushort2(f2bf(ox), f2bf(oy));
  }
}

// ---------------- hyperbolic boundary ops ----------------
__global__ __launch_bounds__(256) void expproj_all_k(
    float* __restrict__ Xk, float* __restrict__ Xq,
    const float* __restrict__ curv, int ci) {
  const int row = blockIdx.x, tid = threadIdx.x;
  float* x = (row < MKT) ? (Xk + (size_t)row * HID)
                         : (Xq + (size_t)(row - MKT) * HID);
  const float c = curv[ci];
  const float Kc = 1.f / c, sqrtK = sqrtf(Kc);
  float ss = 0.f;
  for (int d = 1 + tid; d < HID; d += 256) {
    float v = x[d];
    ss += v * v;
  }
  ss = blockReduceSum256(ss);
  float n = fmaxf(sqrtf(ss), 1e-15f);
  float theta = n / sqrtK;
  float f = sqrtK * sinhf(theta) / n;
  float ss2 = f * f * ss;
  float first = sqrtf(fmaxf(Kc + ss2, 1e-7f));
  for (int d = 1 + tid; d < HID; d += 256) x[d] = f * x[d];
  if (tid == 0) x[0] = first;
}

// in-place proj_tan0(logmap0(x, c)) + bf16 copy
__global__ __launch_bounds__(256) void logmap_kernel(
    float* __restrict__ x_, ushort_t* __restrict__ outb, int D,
    const float* __restrict__ curv, int ci) {
  const int row = blockIdx.x, tid = threadIdx.x;
  float* x = x_ + (size_t)row * D;
  const float c = curv[ci];
  const float Kc = 1.f / c, sqrtK = sqrtf(Kc);
  float x0 = x[0];
  float ss = 0.f;
  for (int d = 1 + tid; d < D; d += 256) {
    float v = x[d];
    ss += v * v;
  }
  ss = blockReduceSum256(ss);
  float n = fmaxf(sqrtf(ss), 1e-15f);
  float theta = fmaxf(x0 / sqrtK, 1.f + 1e-7f);
  float r = sqrtK * acoshf(theta) / n;
  for (int d = 1 + tid; d < D; d += 256) {
    float v = r * x[d];
    x[d] = v;
    outb[(size_t)row * D + d] = f2bf(v);
  }
  if (tid == 0) {
    x[0] = 0.f;
    outb[(size_t)row * D] = 0;
  }
}

// ---------------- tail ----------------
__global__ __launch_bounds__(512) void mean_kernel(
    const float* __restrict__ kx, const float* __restrict__ qx,
    float* __restrict__ last) {
  const int b = blockIdx.x, tid = threadIdx.x;
  float sk = 0.f;
  for (int r = 0; r < NK; ++r) sk += kx[((size_t)b * NK + r) * HID + tid];
  float sq = 0.f;
  for (int r = 0; r < NQ; ++r) sq += qx[((size_t)b * NQ + r) * HID + tid];
  last[(size_t)b * 1024 + tid] = sk * (1.f / NK);
  last[(size_t)b * 1024 + HID + tid] = sq * (1.f / NQ);
}

__global__ __launch_bounds__(512) void logsoftmax_k(float* __restrict__ x) {
  const int b = blockIdx.x, tid = threadIdx.x;
  float4* row = (float4*)(x + (size_t)b * NANS);
  float m = -3.4e38f;
  for (int i = tid; i < NANS / 4; i += 512) {
    float4 v = row[i];
    m = fmaxf(fmaxf(fmaxf(m, v.x), v.y), fmaxf(v.z, v.w));
  }
  m = blockReduceMax512(m);
  float s = 0.f;
  for (int i = tid; i < NANS / 4; i += 512) {
    float4 v = row[i];
    s += expf(v.x - m) + expf(v.y - m) + expf(v.z - m) + expf(v.w - m);
  }
  s = blockReduceSum512(s);
  float lse = m + logf(s);
  for (int i = tid; i < NANS / 4; i += 512) {
    float4 v = row[i];
    v.x -= lse; v.y -= lse; v.z -= lse; v.w -= lse;
    row[i] = v;
  }
}

// ---------------- launch ----------------
extern "C" void kernel_launch(void* const* d_in, const int* in_sizes, int n_in,
                              void* d_out, int out_size, void* d_ws, size_t ws_size,
                              hipStream_t stream) {
  const int* qid = (const int*)d_in[0];
  const int* kid = (const int*)d_in[1];
  const float* emb = (const float*)d_in[2];
  const float* q2h_w = (const float*)d_in[3];
  const float* q2h_b = (const float*)d_in[4];
  const float* k2h_w = (const float*)d_in[5];
  const float* k2h_b = (const float*)d_in[6];
  const float* Wk = (const float*)d_in[7];
  const float* Wq = (const float*)d_in[8];
  const float* curv = (const float*)d_in[9];
  const float* p1w = (const float*)d_in[10];
  const float* p1b = (const float*)d_in[11];
  const float* p2w = (const float*)d_in[12];
  const float* p2b = (const float*)d_in[13];
  const float* glove = (const float*)d_in[14];
  float* out = (float*)d_out;

  // ---- workspace layout ----
  float* f = (float*)d_ws;
  float* Xk = f;                               // 25600*512 (kt, in-place)
  float* Xq0 = Xk + (size_t)MKT * HID;         // 7680*512 (qt ping)
  float* Xq1 = Xq0 + (size_t)MQT * HID;        // 7680*512 (qt pong)
  float* last = Xq1 + (size_t)MQT * HID;       // 256*1024
  float* fend = last + (size_t)BATCH * 1024;

  ushort_t* u = (ushort_t*)fend;
  ushort_t* gk = u;                            // 25600*928 (later gloveb)
  ushort_t* gq = gk + (size_t)MKT * KP;        // 7680*928
  ushort_t* Xkb = gq + (size_t)MQT * KP;       // 25600*512 (kt bf16, in-place)
  ushort_t* kpb = Xkb + (size_t)MKT * HID;     // 25600*512 (kp scratch)
  ushort_t* qb0 = kpb + (size_t)MKT * HID;     // 7680*512 (qt bf16 ping)
  ushort_t* qb1 = qb0 + (size_t)MQT * HID;     // 7680*512 (qp / qt bf16 pong)
  ushort_t* q2h_wt = qb1 + (size_t)MQT * HID;  // 512*928
  ushort_t* k2h_wt = q2h_wt + (size_t)HID * KP;
  ushort_t* Wkt = k2h_wt + (size_t)HID * KP;   // 3*512*512
  ushort_t* Wqt = Wkt + (size_t)NLAYERS * HID * HID;
  ushort_t* p1wt = Wqt + (size_t)NLAYERS * HID * HID;   // 512*1024
  ushort_t* p2wt = p1wt + (size_t)HID * 1024;           // 384*512
  ushort_t* lastb = p2wt + (size_t)NOUTP * HID;         // 256*1024
  ushort_t* h1b = lastb + (size_t)BATCH * 1024;         // 256*512
  ushort_t* o2b = h1b + (size_t)BATCH * HID;            // 256*384
  ushort_t* gloveb = gk;  // overlay [32000][384] (gk dead after input GEMM)

  // ---- pre-casts (merged) ----
  gather_all_k<<<MQT + MKT, 256, 0, stream>>>(qid, kid, emb, gq, gk);
  tcast10_k<<<dim3(16, 32, 10), 256, 0, stream>>>(
      q2h_w, k2h_w, Wk, Wq, p1w, p2w, q2h_wt, k2h_wt, Wkt, Wqt, p1wt, p2wt);

  // ---- input projections (merged q+k), fused proj_tan0 ----
  mfma_gemm2<1, 1, 1, 1, 0><<<dim3(HID / 128, MQT / 128 + MKT / 128), 256, 0, stream>>>(
      gq, q2h_wt, q2h_b, Xq0, qb0, MQT / 128,
      gk, k2h_wt, k2h_b, Xk, Xkb, HID, KP, HID);

  // glove cast (overlays gk, now dead)
  cast_pad_rows_k<<<NANS, 128, 0, stream>>>(glove, gloveb, NOUT, NOUTP);

  // ---- layers in tangent space ----
  float* Xq_cur = Xq0;
  float* Xq_alt = Xq1;
  ushort_t* Xqb_cur = qb0;
  ushort_t* Xqb_alt = qb1;
  for (int i = 0; i < NLAYERS; ++i) {
    mfma_gemm2<0, 0, 1, 0, 0><<<dim3(HID / 128, MKT / 128 + MQT / 128), 256, 0, stream>>>(
        Xkb, Wkt + (size_t)i * HID * HID, nullptr, nullptr, kpb, MKT / 128,
        Xqb_cur, Wqt + (size_t)i * HID * HID, nullptr, nullptr, Xqb_alt, HID, HID, HID);
    att_fused_k<<<BATCH, 256, 0, stream>>>(
        kpb, Xqb_alt, Xqb_cur, Xq_cur, Xq_alt, Xqb_alt, Xk, Xkb);
    float* tf = Xq_cur; Xq_cur = Xq_alt; Xq_alt = tf;
    ushort_t* tu = Xqb_cur; Xqb_cur = Xqb_alt; Xqb_alt = tu;
  }

  // ---- boundary: to hyperbolic, mean, back to tangent ----
  expproj_all_k<<<MKT + MQT, 256, 0, stream>>>(Xk, Xq_cur, curv, NLAYERS);
  mean_kernel<<<BATCH, 512, 0, stream>>>(Xk, Xq_cur, last);
  logmap_kernel<<<BATCH, 256, 0, stream>>>(last, lastb, 1024, curv, NLAYERS);

  // ---- head (all MFMA bf16) ----
  // proj1: [256,1024]@[1024,512] + b, relu -> h1b
  mfma_gemm2<1, 0, 1, 0, 1><<<dim3(HID / 128, BATCH / 128), 256, 0, stream>>>(
      lastb, p1wt, p1b, nullptr, h1b, BATCH / 128,
      lastb, p1wt, p1b, nullptr, h1b, HID, 1024, HID);
  // proj2: [256,512]@[512,300->384] + b -> o2b (pad cols are 0)
  mfma_gemm2<1, 0, 1, 0, 0><<<dim3(NOUTP / 128, BATCH / 128), 256, 0, stream>>>(
      h1b, p2wt, p2b, nullptr, o2b, BATCH / 128,
      h1b, p2wt, p2b, nullptr, o2b, NOUTP, HID, NOUT);
  // sim: [256,384]@[384,32000] -> out f32
  mfma_gemm2<0, 1, 0, 0, 0><<<dim3(NANS / 128, BATCH / 128), 256, 0, stream>>>(
      o2b, gloveb, nullptr, out, nullptr, BATCH / 128,
      o2b, gloveb, nullptr, out, nullptr, NANS, NOUTP, NANS);
  logsoftmax_k<<<BATCH, 512, 0, stream>>>(out);
}